// Round 8
// baseline (590.221 us; speedup 1.0000x reference)
//
#include <hip/hip_runtime.h>
#include <stdint.h>
#include <math.h>

#define B_ 32
#define V_ 2048
#define E_ 12288
#define M_ (B_*V_)

typedef __bf16 bf16x8 __attribute__((ext_vector_type(8)));
typedef float f32x4 __attribute__((ext_vector_type(4)));

__device__ __forceinline__ float bf2f(unsigned short u){
  union { unsigned int i; float f; } v; v.i = ((unsigned int)u) << 16; return v.f;
}
__device__ __forceinline__ unsigned short f2bf(float f){
  union { float f; unsigned int i; } v; v.f = f;
  unsigned int r = (v.i + 0x7fffu + ((v.i >> 16) & 1u)) >> 16;
  return (unsigned short)r;
}
__device__ __forceinline__ void gload16(const unsigned short* g, unsigned short* l){
  __builtin_amdgcn_global_load_lds(
      (const __attribute__((address_space(1))) void*)g,
      (__attribute__((address_space(3))) void*)l, 16, 0, 0);
}

// ---------------- k_pre0: block 0 = CSR build (1024 thr); blocks 1.. = preA work ----------------
__global__ __launch_bounds__(1024) void k_pre0(
    const int* __restrict__ ei, int* __restrict__ rowptr_g, int* __restrict__ cols_g,
    float* __restrict__ vals_g, float* __restrict__ selfw_g,
    float* __restrict__ wsum_g, float* __restrict__ w2_g,
    const float* __restrict__ W3, const float* __restrict__ W4,
    const float* __restrict__ img, const float* __restrict__ W1,
    unsigned short* __restrict__ W3B, unsigned short* __restrict__ W4T,
    float* __restrict__ partB){
  __shared__ int   sdeg[V_];
  __shared__ int   srp[V_ + 1];
  __shared__ int   sfill[V_];
  __shared__ float sdinv[V_];
  __shared__ float swsum[V_];
  __shared__ float sw2[V_];
  __shared__ int   swt[16];
  __shared__ __align__(16) float tile[4][32][33];
  if (blockIdx.x == 0){
    const int t = threadIdx.x;
    sdeg[2*t] = 0; sdeg[2*t+1] = 0; sfill[2*t] = 0; sfill[2*t+1] = 0;
    __syncthreads();
    #pragma unroll
    for (int e = t; e < E_; e += 1024) atomicAdd(&sdeg[ei[E_ + e]], 1);
    __syncthreads();
    int c0 = sdeg[2*t], c1 = sdeg[2*t+1];
    int s2 = c0 + c1;
    int lane = t & 63, wid = t >> 6;
    int pre = s2;
    #pragma unroll
    for (int off = 1; off < 64; off <<= 1){
      int u = __shfl_up(pre, off);
      if (lane >= off) pre += u;
    }
    if (lane == 63) swt[wid] = pre;
    __syncthreads();
    if (t == 0){
      int run = 0;
      #pragma unroll
      for (int i = 0; i < 16; i++){ int x = swt[i]; swt[i] = run; run += x; }
      srp[V_] = run;
    }
    __syncthreads();
    int base = swt[wid] + (pre - s2);
    srp[2*t] = base; srp[2*t+1] = base + c0;
    #pragma unroll
    for (int v = t; v < V_; v += 1024){
      float d = (float)(sdeg[v] + 1);
      float di = rsqrtf(d);
      sdinv[v] = di;
      swsum[v] = di * di;
    }
    __syncthreads();
    #pragma unroll
    for (int e = t; e < E_; e += 1024){
      int s = ei[e], d = ei[E_ + e];
      int pos = srp[d] + atomicAdd(&sfill[d], 1);
      float val = sdinv[s] * sdinv[d];
      cols_g[pos] = s;
      vals_g[pos] = val;
      atomicAdd(&swsum[d], val);
    }
    __syncthreads();
    #pragma unroll
    for (int v = t; v < V_; v += 1024)
      sw2[v] = (sdinv[v] * sdinv[v]) * swsum[v];
    __syncthreads();
    #pragma unroll
    for (int e = t; e < E_; e += 1024){
      int s = ei[e], d = ei[E_ + e];
      atomicAdd(&sw2[d], sdinv[s] * sdinv[d] * swsum[s]);
    }
    __syncthreads();
    #pragma unroll
    for (int v = t; v < V_; v += 1024){
      rowptr_g[v] = srp[v];
      selfw_g[v]  = sdinv[v] * sdinv[v];
      wsum_g[v]   = swsum[v];
      w2_g[v]     = sw2[v];
    }
    if (t == 0) rowptr_g[V_] = srp[V_];
  } else {
    // preA: 4 sub-blocks of 256 threads each; region boundaries are 4-aligned
    int u = blockIdx.x - 1;
    int t10 = threadIdx.x;
    int sub = (u << 2) + (t10 >> 8);
    int t = t10 & 255;
    int ti = t10 >> 8;
    if (sub < 256){
      int tr0 = (sub >> 4) << 5, tc0 = (sub & 15) << 5;
      int r = t >> 5, c = t & 31;
      #pragma unroll
      for (int i = 0; i < 4; i++)
        tile[ti][r + 8*i][c] = W4[(size_t)(tr0 + r + 8*i) * 512 + tc0 + c];
      __syncthreads();
      #pragma unroll
      for (int i = 0; i < 4; i++)
        W4T[(size_t)(tc0 + r + 8*i) * 512 + tr0 + c] = f2bf(tile[ti][c][r + 8*i]);
    } else if (sub < 256 + 1024){
      int id = (sub - 256) * 256 + t;
      W3B[id] = f2bf(W3[id]);
    } else {
      // I1 partial GEMM: g in [0,64): kc = g>>1 (32 k-chunks of 16), nh = g&1
      int g = sub - 1280;
      int kc = g >> 1, nh = g & 1;
      int k0 = kc * 16;
      float* xs = &tile[ti][0][0];            // 512 floats, 16B-aligned slice
      for (int i = t; i < 512; i += 256)
        xs[i] = img[(size_t)(i >> 4) * 512 + k0 + (i & 15)];
      __syncthreads();
      const float* W = W1 + 3 * 512;
      int n = (nh << 8) + t;
      float acc[32] = {};
      #pragma unroll
      for (int kg = 0; kg < 4; kg++){
        const float* wp = W + (size_t)(k0 + kg * 4) * 512 + n;
        float w0 = wp[0], w1 = wp[512], w2 = wp[1024], w3 = wp[1536];
        #pragma unroll
        for (int r = 0; r < 32; r++){
          f32x4 xv = *(const f32x4*)&xs[r * 16 + kg * 4];
          acc[r] += xv[0]*w0 + xv[1]*w1 + xv[2]*w2 + xv[3]*w3;
        }
      }
      float* p = partB + (size_t)kc * 16384 + n;
      #pragma unroll
      for (int r = 0; r < 32; r++) p[(size_t)r * 512] = acc[r];
    }
  }
}

// ---------------- preB: I1 reduce (32 partials) + small weight products ----------------
__global__ __launch_bounds__(256) void k_preB(
    const float* __restrict__ partB, float* __restrict__ I1,
    const float* __restrict__ b3, const float* __restrict__ W4,
    const float* __restrict__ W5, const float* __restrict__ W6,
    const float* __restrict__ b5,
    float* __restrict__ C34, float* __restrict__ W56, float* __restrict__ C56){
  int blk = blockIdx.x, t = threadIdx.x;
  if (blk < 64){
    int id = blk * 256 + t;
    float a = 0.f;
    #pragma unroll
    for (int s = 0; s < 32; s++) a += partB[(size_t)s * 16384 + id];
    I1[id] = a;
  } else {
    int id = (blk - 64) * 256 + t;
    if (id < 512){
      float a0=0,a1=0,a2=0,a3=0;
      for (int k = 0; k < 512; k += 4){
        a0 += b3[k]   * W4[(size_t)k * 512 + id];
        a1 += b3[k+1] * W4[(size_t)(k+1) * 512 + id];
        a2 += b3[k+2] * W4[(size_t)(k+2) * 512 + id];
        a3 += b3[k+3] * W4[(size_t)(k+3) * 512 + id];
      }
      C34[id] = a0+a1+a2+a3;
    } else if (id < 512 + 1536){
      int i = id - 512; int k5 = i / 3, j = i % 3;
      float a = 0.f;
      #pragma unroll 4
      for (int u = 0; u < 64; u++) a += W5[k5 * 64 + u] * W6[u * 3 + j];
      W56[i] = a;
    } else if (id < 512 + 1536 + 3){
      int j = id - (512 + 1536);
      float a = 0.f;
      #pragma unroll 4
      for (int u = 0; u < 64; u++) a += b5[u] * W6[u * 3 + j];
      C56[j] = a;
    }
  }
}

// ---------------- preC: P split-K partials (32x16 chunks), LDS-staged CAT = [b1; W1 rows 0-2; I1] ----------------
__global__ __launch_bounds__(256) void k_preC(
    const float* __restrict__ b1, const float* __restrict__ W1,
    const float* __restrict__ I1, const float* __restrict__ W2,
    float* __restrict__ partB){
  __shared__ __align__(16) float xs[36 * 16];
  int g = blockIdx.x;               // 64 blocks: kc = g>>1, nh = g&1
  int kc = g >> 1, k0 = kc * 16;
  int t = threadIdx.x;
  int n = ((g & 1) << 8) + t;
  for (int i = t; i < 576; i += 256){
    int r = i >> 4, kk = i & 15;
    const float* q;
    if (r == 0)      q = b1;
    else if (r < 4)  q = W1 + (size_t)(r - 1) * 512;
    else             q = I1 + (size_t)(r - 4) * 512;
    xs[i] = q[k0 + kk];
  }
  __syncthreads();
  float acc[36] = {};
  #pragma unroll
  for (int kg = 0; kg < 4; kg++){
    const float* wp = W2 + (size_t)(k0 + kg * 4) * 512 + n;
    float w0 = wp[0], w1 = wp[512], w2 = wp[1024], w3 = wp[1536];
    #pragma unroll
    for (int r = 0; r < 36; r++){
      f32x4 xv = *(const f32x4*)&xs[r * 16 + kg * 4];
      acc[r] += xv[0]*w0 + xv[1]*w1 + xv[2]*w2 + xv[3]*w3;
    }
  }
  float* p = partB + (size_t)kc * 18432 + n;
  #pragma unroll
  for (int r = 0; r < 36; r++) p[(size_t)r * 512] = acc[r];
}

// ---------------- preD: P reduce (32 partials) ----------------
__global__ __launch_bounds__(256) void k_preD(
    const float* __restrict__ partB, float* __restrict__ P){
  int id = blockIdx.x * 256 + threadIdx.x;
  float a = 0.f;
  #pragma unroll
  for (int s = 0; s < 32; s++) a += partB[(size_t)s * 18432 + id];
  P[id] = a;
}

// ---------------- k_va2a / k_va2b: A^2 on vertices, split into 2 kernels x 256 blocks ----------------
__global__ __launch_bounds__(256) void k_va2a(
    const float* __restrict__ in, const int* __restrict__ rowptr,
    const int* __restrict__ cols, const float* __restrict__ vals,
    const float* __restrict__ selfw, float* __restrict__ yout){
  __shared__ float xs[V_ * 3];
  int b = blockIdx.y, t = threadIdx.x;
  const float* ib = in + (size_t)b * V_ * 3;
  for (int i = t; i < V_ * 3; i += 256) xs[i] = ib[i];
  __syncthreads();
  int v = blockIdx.x * 256 + t;
  float sw = selfw[v];
  float a0 = sw * xs[v*3], a1 = sw * xs[v*3+1], a2 = sw * xs[v*3+2];
  int re = rowptr[v + 1];
  for (int e = rowptr[v]; e < re; e++){
    int s = cols[e]; float vv = vals[e];
    a0 += vv * xs[s*3]; a1 += vv * xs[s*3+1]; a2 += vv * xs[s*3+2];
  }
  float* o = yout + (size_t)b * V_ * 3 + v * 3;
  o[0] = a0; o[1] = a1; o[2] = a2;
}

__global__ __launch_bounds__(256) void k_va2b(
    const float* __restrict__ yin, const int* __restrict__ rowptr,
    const int* __restrict__ cols, const float* __restrict__ vals,
    const float* __restrict__ selfw, float* __restrict__ outv){
  __shared__ float xs[V_ * 3];
  int b = blockIdx.y, t = threadIdx.x;
  const float* ib = yin + (size_t)b * V_ * 3;
  for (int i = t; i < V_ * 3; i += 256) xs[i] = ib[i];
  __syncthreads();
  int v = blockIdx.x * 256 + t;
  float sw = selfw[v];
  float a0 = sw * xs[v*3], a1 = sw * xs[v*3+1], a2 = sw * xs[v*3+2];
  int re = rowptr[v + 1];
  for (int e = rowptr[v]; e < re; e++){
    int s = cols[e]; float vv = vals[e];
    a0 += vv * xs[s*3]; a1 += vv * xs[s*3+1]; a2 += vv * xs[s*3+2];
  }
  float* o = outv + ((size_t)v * 32 + b) * 3;
  o[0] = a0; o[1] = a1; o[2] = a2;
}

// ---------------- k_x2: layer-2 transform, computed ONCE per (v,b,f). H bf16 vertex-major ----------------
__global__ __launch_bounds__(1024) void k_x2(
    const float* __restrict__ va2v, const float* __restrict__ P,
    const float* __restrict__ wsum, const float* __restrict__ w2s,
    const float* __restrict__ b2,
    unsigned short* __restrict__ Y){
  int v = (blockIdx.x << 2) + (threadIdx.x >> 8);
  int batch = (blockIdx.y << 2) + ((threadIdx.x >> 6) & 3);
  int f8 = (threadIdx.x & 63) * 8;
  const float* va = va2v + ((size_t)v * 32 + batch) * 3;
  float x0 = va[0], x1 = va[1], x2 = va[2];
  float w2v = w2s[v], wsv = wsum[v];
  float tt[8];
  #pragma unroll
  for (int h = 0; h < 2; h++){
    f32x4 wv0 = *(const f32x4*)&P[512  + f8 + 4*h];
    f32x4 wv1 = *(const f32x4*)&P[1024 + f8 + 4*h];
    f32x4 wv2 = *(const f32x4*)&P[1536 + f8 + 4*h];
    f32x4 ccv = *(const f32x4*)&P[f8 + 4*h];
    f32x4 bbv = *(const f32x4*)&b2[f8 + 4*h];
    f32x4 iiv = *(const f32x4*)&P[2048 + (size_t)batch * 512 + f8 + 4*h];
    #pragma unroll
    for (int j = 0; j < 4; j++){
      float tv = x0*wv0[j] + x1*wv1[j] + x2*wv2[j] + w2v*iiv[j] + wsv*ccv[j] + bbv[j];
      tt[4*h + j] = fmaxf(tv, 0.f);
    }
  }
  unsigned int o[4];
  #pragma unroll
  for (int i = 0; i < 4; i++)
    o[i] = (unsigned int)f2bf(tt[2*i]) | ((unsigned int)f2bf(tt[2*i+1]) << 16);
  *(uint4*)&Y[((size_t)v * 32 + batch) * 512 + f8] = *(uint4*)o;
}

// ---------------- k_aggp: F=512 bf16 A-hop, 1MB-per-XCD L2 phases ----------------
// CLEAN version of the r4 experiment (without the NT-store confound). bid bits:
// [fc(1) | bgHi(2) | dstQuad(9) | xcd(3)], 32768 blocks x 256 thr (4 waves, 1 dst/wave).
// batch = bgHi*8 + xcd: at any time each XCD works ONE batch x 256 features ->
// resident slice = 2048v x 256f x 2B = 1MB in + 1MB out + CSR (~100KB) << 4MB L2.
// fc/bgHi are time-major phases. Wave-uniform dst, per-lane uint2 (4 bf16), identical
// summation order to the proven k_aggv (same numerics).
__global__ __launch_bounds__(256) void k_aggp(
    const unsigned short* __restrict__ Hg, const int* __restrict__ rowptr,
    const int* __restrict__ cols, const float* __restrict__ vals,
    const float* __restrict__ selfw, unsigned short* __restrict__ Xo){
  int bid = blockIdx.x;
  int xcd  = bid & 7;
  int dstQ = (bid >> 3) & 511;
  int bgHi = (bid >> 12) & 3;
  int fc   = bid >> 14;
  int batch = bgHi * 8 + xcd;
  int wave = threadIdx.x >> 6, lane = threadIdx.x & 63;
  int dst = dstQ * 4 + wave;
  size_t base = (size_t)batch * 512 + fc * 256 + lane * 4;
  int rs = rowptr[dst], re = rowptr[dst + 1];
  float sw = selfw[dst];
  float a0, a1, a2, a3;
  {
    uint2 q = *(const uint2*)&Hg[(size_t)dst * 16384 + base];
    a0 = sw * bf2f(q.x & 0xffff); a1 = sw * bf2f(q.x >> 16);
    a2 = sw * bf2f(q.y & 0xffff); a3 = sw * bf2f(q.y >> 16);
  }
  int e = rs;
  for (; e + 1 < re; e += 2){
    int s0 = cols[e], s1 = cols[e+1];
    float v0 = vals[e], v1 = vals[e+1];
    uint2 p0 = *(const uint2*)&Hg[(size_t)s0 * 16384 + base];
    uint2 p1 = *(const uint2*)&Hg[(size_t)s1 * 16384 + base];
    a0 += v0 * bf2f(p0.x & 0xffff) + v1 * bf2f(p1.x & 0xffff);
    a1 += v0 * bf2f(p0.x >> 16)    + v1 * bf2f(p1.x >> 16);
    a2 += v0 * bf2f(p0.y & 0xffff) + v1 * bf2f(p1.y & 0xffff);
    a3 += v0 * bf2f(p0.y >> 16)    + v1 * bf2f(p1.y >> 16);
  }
  if (e < re){
    int s = cols[e]; float v = vals[e];
    uint2 p = *(const uint2*)&Hg[(size_t)s * 16384 + base];
    a0 += v * bf2f(p.x & 0xffff); a1 += v * bf2f(p.x >> 16);
    a2 += v * bf2f(p.y & 0xffff); a3 += v * bf2f(p.y >> 16);
  }
  uint2 o;
  o.x = (unsigned int)f2bf(a0) | ((unsigned int)f2bf(a1) << 16);
  o.y = (unsigned int)f2bf(a2) | ((unsigned int)f2bf(a3) << 16);
  *(uint2*)&Xo[(size_t)dst * 16384 + base] = o;
}

// ---------------- bf16 MFMA GEMM, A/B dbuf via global_load_lds, 1 barrier/iter ----------------
template<int BM, int BN, int WM, int WN, int TM, int TN>
__global__ __launch_bounds__(WM*WN*64) void k_gemm(
    const unsigned short* __restrict__ Xg, const unsigned short* __restrict__ Wt,
    unsigned short* __restrict__ Hg, int K, int N,
    const float* __restrict__ wsumv, const float* __restrict__ cvec,
    const float* __restrict__ bias, int relu,
    const float* __restrict__ W56g, float* __restrict__ h5p){
  constexpr int BK = 32;
  constexpr int NW = WM * WN;
  constexpr int NT = NW * 64;
  constexpr int RA = BM / NW;
  constexpr int RB = BN / NW;
  __shared__ __align__(16) unsigned short As[2][BM * BK];
  __shared__ __align__(16) unsigned short Bs[2][BN * BK];
  __shared__ float h5s[BM * 3];
  const int tid = threadIdx.x;
  const int row0 = blockIdx.x * BM, col0 = blockIdx.y * BN;
  const int wave = tid >> 6, lane = tid & 63;
  const int wr = wave / WN, wc = wave % WN;
  const int lrow = lane & 15, lq = lane >> 4;
  const int lrw = lane >> 2, lcol = (lane & 3) * 8;
  const int arow = wave * RA, brow = wave * RB;
  if (h5p){
    for (int i = tid; i < BM * 3; i += NT) h5s[i] = 0.f;
  }
  f32x4 acc[TM][TN] = {};
  #pragma unroll
  for (int t = 0; t < RA / 16; t++)
    gload16(&Xg[(size_t)(row0 + arow + t * 16 + lrw) * K + lcol],
            &As[0][(arow + t * 16) * BK]);
  #pragma unroll
  for (int t = 0; t < RB / 16; t++)
    gload16(&Wt[(size_t)(col0 + brow + t * 16 + lrw) * K + lcol],
            &Bs[0][(brow + t * 16) * BK]);
  int cur = 0;
  for (int k0 = 0; k0 < K; k0 += BK){
    __syncthreads();
    if (k0 + BK < K){
      #pragma unroll
      for (int t = 0; t < RA / 16; t++)
        gload16(&Xg[(size_t)(row0 + arow + t * 16 + lrw) * K + k0 + BK + lcol],
                &As[cur ^ 1][(arow + t * 16) * BK]);
      #pragma unroll
      for (int t = 0; t < RB / 16; t++)
        gload16(&Wt[(size_t)(col0 + brow + t * 16 + lrw) * K + k0 + BK + lcol],
                &Bs[cur ^ 1][(brow + t * 16) * BK]);
    }
    bf16x8 af[TM], bfr[TN];
    #pragma unroll
    for (int tm = 0; tm < TM; tm++)
      af[tm] = *(const bf16x8*)&As[cur][(wr * TM * 16 + tm * 16 + lrow) * BK + lq * 8];
    #pragma unroll
    for (int tn = 0; tn < TN; tn++)
      bfr[tn] = *(const bf16x8*)&Bs[cur][(wc * TN * 16 + tn * 16 + lrow) * BK + lq * 8];
    #pragma unroll
    for (int tm = 0; tm < TM; tm++)
      #pragma unroll
      for (int tn = 0; tn < TN; tn++)
        acc[tm][tn] = __builtin_amdgcn_mfma_f32_16x16x32_bf16(af[tm], bfr[tn], acc[tm][tn], 0, 0, 0);
    cur ^= 1;
  }
  if (h5p){
    // fused epilogue: relu(acc + wsum*cv + bv) . W56-slice -> block partial
    float w56l[TN][3], cvl[TN], bvl[TN];
    #pragma unroll
    for (int tn = 0; tn < TN; tn++){
      int col = col0 + wc * TN * 16 + tn * 16 + lrow;
      cvl[tn] = cvec[col]; bvl[tn] = bias[col];
      w56l[tn][0] = W56g[col * 3];
      w56l[tn][1] = W56g[col * 3 + 1];
      w56l[tn][2] = W56g[col * 3 + 2];
    }
    #pragma unroll
    for (int tm = 0; tm < TM; tm++){
      #pragma unroll
      for (int r = 0; r < 4; r++){
        int lr = wr * TM * 16 + tm * 16 + lq * 4 + r;
        float ws = wsumv[(row0 + lr) >> 5];
        float p0 = 0.f, p1 = 0.f, p2 = 0.f;
        #pragma unroll
        for (int tn = 0; tn < TN; tn++){
          float x = fmaxf(acc[tm][tn][r] + ws * cvl[tn] + bvl[tn], 0.f);
          p0 += x * w56l[tn][0]; p1 += x * w56l[tn][1]; p2 += x * w56l[tn][2];
        }
        #pragma unroll
        for (int off = 8; off; off >>= 1){
          p0 += __shfl_down(p0, off);
          p1 += __shfl_down(p1, off);
          p2 += __shfl_down(p2, off);
        }
        if (lrow == 0){
          atomicAdd(&h5s[lr * 3 + 0], p0);
          atomicAdd(&h5s[lr * 3 + 1], p1);
          atomicAdd(&h5s[lr * 3 + 2], p2);
        }
      }
    }
    __syncthreads();
    float* dst = h5p + (size_t)blockIdx.y * ((size_t)M_ * 3) + (size_t)row0 * 3;
    for (int i = tid; i < BM * 3; i += NT) dst[i] = h5s[i];
  } else {
    #pragma unroll
    for (int tm = 0; tm < TM; tm++){
      #pragma unroll
      for (int tn = 0; tn < TN; tn++){
        int col = col0 + wc * TN * 16 + tn * 16 + lrow;
        float cv = 0.f, bv = 0.f;
        if (cvec){ cv = cvec[col]; bv = bias[col]; }
        #pragma unroll
        for (int r = 0; r < 4; r++){
          int row = row0 + wr * TM * 16 + tm * 16 + lq * 4 + r;
          float x = acc[tm][tn][r];
          if (cvec) x += wsumv[row >> 5] * cv + bv;
          if (relu) x = fmaxf(x, 0.f);
          Hg[(size_t)row * N + col] = f2bf(x);
        }
      }
    }
  }
}

// ---------------- k_xa2a / k_xa2b: layers 5+6 tail split into 2 kernels x 256 blocks ----------------
__global__ __launch_bounds__(256) void k_xa2a(
    const float* __restrict__ h5p, const int* __restrict__ rowptr,
    const int* __restrict__ cols, const float* __restrict__ vals,
    const float* __restrict__ selfw, float* __restrict__ yout){
  __shared__ float xs[V_ * 3];
  int b = blockIdx.y, t = threadIdx.x;
  const size_t M3 = (size_t)M_ * 3;
  for (int i = t; i < V_ * 3; i += 256){
    int v = i / 3, j = i - v * 3;
    size_t g = ((size_t)v * 32 + b) * 3 + j;
    xs[i] = h5p[g] + h5p[M3 + g] + h5p[2 * M3 + g] + h5p[3 * M3 + g];
  }
  __syncthreads();
  int v = blockIdx.x * 256 + t;
  float sw = selfw[v];
  float a0 = sw * xs[v*3], a1 = sw * xs[v*3+1], a2 = sw * xs[v*3+2];
  int re = rowptr[v + 1];
  for (int e = rowptr[v]; e < re; e++){
    int s = cols[e]; float vv = vals[e];
    a0 += vv * xs[s*3]; a1 += vv * xs[s*3+1]; a2 += vv * xs[s*3+2];
  }
  float* o = yout + (size_t)b * V_ * 3 + v * 3;
  o[0] = a0; o[1] = a1; o[2] = a2;
}

__global__ __launch_bounds__(256) void k_xa2b(
    const float* __restrict__ yin, const int* __restrict__ rowptr,
    const int* __restrict__ cols, const float* __restrict__ vals,
    const float* __restrict__ selfw, const float* __restrict__ wsum,
    const float* __restrict__ C56, const float* __restrict__ b6,
    float* __restrict__ XF){
  __shared__ float xs[V_ * 3];
  int b = blockIdx.y, t = threadIdx.x;
  const float* ib = yin + (size_t)b * V_ * 3;
  for (int i = t; i < V_ * 3; i += 256) xs[i] = ib[i];
  __syncthreads();
  int v = blockIdx.x * 256 + t;
  float sw = selfw[v];
  float a0 = sw * xs[v*3], a1 = sw * xs[v*3+1], a2 = sw * xs[v*3+2];
  int re = rowptr[v + 1];
  for (int e = rowptr[v]; e < re; e++){
    int s = cols[e]; float vv = vals[e];
    a0 += vv * xs[s*3]; a1 += vv * xs[s*3+1]; a2 += vv * xs[s*3+2];
  }
  float w = wsum[v];
  a0 = fmaxf(a0 + w * C56[0] + b6[0], 0.f);
  a1 = fmaxf(a1 + w * C56[1] + b6[1], 0.f);
  a2 = fmaxf(a2 + w * C56[2] + b6[2], 0.f);
  float* ob = XF + (size_t)b * V_ * 3 + v * 3;
  ob[0] = a0; ob[1] = a1; ob[2] = a2;
}

// ---------------- FC split-K stage A ----------------
template<int R, int KC>
__global__ __launch_bounds__(256) void k_fcp(
    const float* __restrict__ in, const float* __restrict__ W,
    float* __restrict__ partial, int K, int N){
  const int n = blockIdx.x * 256 + threadIdx.x;
  const int k0 = blockIdx.y * KC;
  float acc[R] = {};
  for (int kk = 0; kk < KC; kk += 4){
    const float* wp = W + (size_t)(k0 + kk) * N + n;
    float w0 = wp[0];
    float w1 = wp[(size_t)N];
    float w2 = wp[(size_t)2 * N];
    float w3 = wp[(size_t)3 * N];
    #pragma unroll
    for (int r = 0; r < R; r++){
      const float* xp = in + (size_t)r * K + k0 + kk;
      acc[r] += xp[0]*w0 + xp[1]*w1 + xp[2]*w2 + xp[3]*w3;
    }
  }
  float* p = partial + (size_t)blockIdx.y * R * N + n;
  #pragma unroll
  for (int r = 0; r < R; r++) p[(size_t)r * N] = acc[r];
}

// ---------------- FC split-K stage B ----------------
__global__ __launch_bounds__(256) void k_fcr(
    const float* __restrict__ partial, const float* __restrict__ bias,
    float* __restrict__ out, int total, int N, int KS, int mode,
    const float* __restrict__ vert){
  int id = blockIdx.x * 256 + threadIdx.x;
  if (id >= total) return;
  int n = id % N;
  float a0 = 0.f, a1 = 0.f, a2 = 0.f, a3 = 0.f;
  int s = 0;
  for (; s + 4 <= KS; s += 4){
    a0 += partial[(size_t)s * total + id];
    a1 += partial[(size_t)(s + 1) * total + id];
    a2 += partial[(size_t)(s + 2) * total + id];
    a3 += partial[(size_t)(s + 3) * total + id];
  }
  for (; s < KS; s++) a0 += partial[(size_t)s * total + id];
  float acc = a0 + a1 + a2 + a3;
  if (bias) acc += bias[n];
  if (mode) acc = vert[id] + 0.1f * tanhf(acc);
  out[id] = acc;
}

// ---------------- workspace layout ----------------
static constexpr size_t AL(size_t x){ return (x + 255) & ~(size_t)255; }
static constexpr size_t S512 = (size_t)M_ * 512 * 2;
static constexpr size_t S3   = (size_t)M_ * 3 * 4;
static constexpr size_t OXA  = 0;
static constexpr size_t OXB  = OXA  + AL(S512);
static constexpr size_t OVA2 = OXB  + AL(S512);
static constexpr size_t OH5P = OVA2 + AL(S3);
static constexpr size_t OXF  = OH5P + AL(4 * S3);
static constexpr size_t OFC1 = OXF  + AL(S3);
static constexpr size_t OFC2 = OFC1 + AL((size_t)B_ * 1024 * 4);
static constexpr size_t OI1  = OFC2 + AL((size_t)B_ * 1024 * 4);
static constexpr size_t OP   = OI1  + AL((size_t)32 * 512 * 4);
static constexpr size_t OC34 = OP   + AL((size_t)36 * 512 * 4);
static constexpr size_t OW56 = OC34 + AL((size_t)512 * 4);
static constexpr size_t OC56 = OW56 + AL((size_t)512 * 3 * 4);
static constexpr size_t OW3B = OC56 + AL((size_t)3 * 4);
static constexpr size_t OW4T = OW3B + AL((size_t)512 * 512 * 2);
static constexpr size_t OW34 = OW4T + AL((size_t)512 * 512 * 2);
static constexpr size_t OROW = OW34 + AL((size_t)512 * 512 * 2);
static constexpr size_t OCOL = OROW + AL((size_t)(V_ + 1) * 4);
static constexpr size_t OVAL = OCOL + AL((size_t)E_ * 4);
static constexpr size_t OSELF= OVAL + AL((size_t)E_ * 4);
static constexpr size_t OWS  = OSELF+ AL((size_t)V_ * 4);
static constexpr size_t OW2S = OWS  + AL((size_t)V_ * 4);

extern "C" void kernel_launch(void* const* d_in, const int* in_sizes, int n_in,
                              void* d_out, int out_size, void* d_ws, size_t ws_size,
                              hipStream_t stream){
  const float* vert  = (const float*)d_in[0];
  const float* img   = (const float*)d_in[1];
  const int*   ei    = (const int*)  d_in[2];
  const float* W1 = (const float*)d_in[3],  *b1 = (const float*)d_in[4];
  const float* W2 = (const float*)d_in[5],  *b2 = (const float*)d_in[6];
  const float* W3 = (const float*)d_in[7],  *b3 = (const float*)d_in[8];
  const float* W4 = (const float*)d_in[9],  *b4 = (const float*)d_in[10];
  const float* W5 = (const float*)d_in[11], *b5 = (const float*)d_in[12];
  const float* W6 = (const float*)d_in[13], *b6 = (const float*)d_in[14];
  const float* fcW1 = (const float*)d_in[15], *fcb1 = (const float*)d_in[16];
  const float* fcW2 = (const float*)d_in[17], *fcb2 = (const float*)d_in[18];
  const float* fcW3 = (const float*)d_in[19], *fcb3 = (const float*)d_in[20];
  float* out = (float*)d_out;

  char* ws = (char*)d_ws;
  unsigned short* XA  = (unsigned short*)(ws + OXA);
  unsigned short* XB  = (unsigned short*)(ws + OXB);
  float* VA2v = (float*)(ws + OVA2);
  float* H5P  = (float*)(ws + OH5P);
  float* XF   = (float*)(ws + OXF);
  float* FC1o = (float*)(ws + OFC1);
  float* FC2o = (float*)(ws + OFC2);
  float* I1   = (float*)(ws + OI1);
  float* P    = (float*)(ws + OP);
  float* C34  = (float*)(ws + OC34);
  float* W56  = (float*)(ws + OW56);
  float* C56  = (float*)(ws + OC56);
  unsigned short* W3B = (unsigned short*)(ws + OW3B);
  unsigned short* W4T = (unsigned short*)(ws + OW4T);
  unsigned short* W34 = (unsigned short*)(ws + OW34);
  float* PARTA = (float*)(ws + OXA);
  float* PARTB = (float*)(ws + OXB);
  float* YTMP  = (float*)(ws + OXA);   // hop intermediate; OXA region idle at those points
  int*   ROW  = (int*)(ws + OROW);
  int*   COL  = (int*)(ws + OCOL);
  float* VAL  = (float*)(ws + OVAL);
  float* SELF = (float*)(ws + OSELF);
  float* WSUM = (float*)(ws + OWS);
  float* W2S  = (float*)(ws + OW2S);

  // ---- CSR (block 0) + preA (blocks 1..336), fused ----
  k_pre0<<<337, 1024, 0, stream>>>(ei, ROW, COL, VAL, SELF, WSUM, W2S,
                                   W3, W4, img, W1, W3B, W4T, PARTB);
  k_preB<<<64 + 9, 256, 0, stream>>>(PARTB, I1, b3, W4, W5, W6, b5, C34, W56, C56);
  k_preC<<<64, 256, 0, stream>>>(b1, W1, I1, W2, PARTB);
  k_preD<<<72, 256, 0, stream>>>(PARTB, P);
  k_gemm<64,64,2,2,2,2><<<dim3(8, 8), 256, 0, stream>>>(W4T, W3B, W34, 512, 512,
                                                        nullptr, nullptr, nullptr, 0,
                                                        nullptr, nullptr);

  // ---- layers 1-2: VA2 split (2 x 256 blocks), transform once (k_x2), two L2-phased A-hops ----
  k_va2a<<<dim3(8, B_), 256, 0, stream>>>(vert, ROW, COL, VAL, SELF, YTMP);
  k_va2b<<<dim3(8, B_), 256, 0, stream>>>(YTMP, ROW, COL, VAL, SELF, VA2v);
  k_x2<<<dim3(V_ / 4, 8), 1024, 0, stream>>>(VA2v, P, WSUM, W2S, b2, XA);
  k_aggp<<<32768, 256, 0, stream>>>(XA, ROW, COL, VAL, SELF, XB);
  k_aggp<<<32768, 256, 0, stream>>>(XB, ROW, COL, VAL, SELF, XA);

  // ---- GEMM w/ fused epilogue AND fused W56 contraction ----
  k_gemm<128,128,2,2,4,4><<<dim3(M_ / 128, 4), 256, 0, stream>>>(XA, W34, XB, 512, 512,
                                                                 WSUM, C34, b4, 1,
                                                                 W56, H5P);

  // ---- layers 5+6 tail: split A^2 (F=3) + epilogue, 2 x 256 blocks ----
  k_xa2a<<<dim3(8, B_), 256, 0, stream>>>(H5P, ROW, COL, VAL, SELF, YTMP);
  k_xa2b<<<dim3(8, B_), 256, 0, stream>>>(YTMP, ROW, COL, VAL, SELF, WSUM, C56, b6, XF);

  // ---- FC head ----
  k_fcp<32,64><<<dim3(4, 96), 256, 0, stream>>>(XF, fcW1, PARTA, 6144, 1024);
  k_fcr<<<(B_ * 1024 + 255) / 256, 256, 0, stream>>>(PARTA, fcb1, FC1o, 32 * 1024, 1024, 96, 0, nullptr);
  k_fcp<32,64><<<dim3(4, 16), 256, 0, stream>>>(FC1o, fcW2, PARTA, 1024, 1024);
  k_fcr<<<(B_ * 1024 + 255) / 256, 256, 0, stream>>>(PARTA, fcb2, FC2o, 32 * 1024, 1024, 16, 0, nullptr);
  k_fcp<32,64><<<dim3(24, 16), 256, 0, stream>>>(FC2o, fcW3, PARTA, 1024, 6144);
  k_fcr<<<(B_ * 6144 + 255) / 256, 256, 0, stream>>>(PARTA, fcb3, out, 32 * 6144, 6144, 16, 1, vert);
}

// Round 9
// 498.166 us; speedup vs baseline: 1.1848x; 1.1848x over previous
//
#include <hip/hip_runtime.h>
#include <stdint.h>
#include <math.h>

#define B_ 32
#define V_ 2048
#define E_ 12288
#define M_ (B_*V_)

typedef __bf16 bf16x8 __attribute__((ext_vector_type(8)));
typedef float f32x4 __attribute__((ext_vector_type(4)));

__device__ __forceinline__ float bf2f(unsigned short u){
  union { unsigned int i; float f; } v; v.i = ((unsigned int)u) << 16; return v.f;
}
__device__ __forceinline__ unsigned short f2bf(float f){
  union { float f; unsigned int i; } v; v.f = f;
  unsigned int r = (v.i + 0x7fffu + ((v.i >> 16) & 1u)) >> 16;
  return (unsigned short)r;
}
__device__ __forceinline__ void gload16(const unsigned short* g, unsigned short* l){
  __builtin_amdgcn_global_load_lds(
      (const __attribute__((address_space(1))) void*)g,
      (__attribute__((address_space(3))) void*)l, 16, 0, 0);
}

// ---------------- k_pre0: block 0 = CSR build (1024 thr); blocks 1.. = preA work ----------------
// preA sub-block regions (256 thr each, no barrier mixing across region boundaries):
//   [0,256)      W4 transpose (uses LDS tile + __syncthreads; whole blocks, u<=63)
//   [256,1280)   W3 -> bf16
//   [1280,1344)  I1 img-GEMM partials (LDS staging + __syncthreads; whole blocks u=320..335)
//   [1344,1346)  C34 = b3 . W4            (folded from old k_preB; no LDS)
//   [1346,1352)  W56 = W5 @ W6            (no LDS)
//   [1352]       C56 = b5 . W6 (3 thr)    (no LDS)
__global__ __launch_bounds__(1024) void k_pre0(
    const int* __restrict__ ei, int* __restrict__ rowptr_g, int* __restrict__ cols_g,
    float* __restrict__ vals_g, float* __restrict__ selfw_g,
    float* __restrict__ wsum_g, float* __restrict__ w2_g,
    const float* __restrict__ W3, const float* __restrict__ W4,
    const float* __restrict__ img, const float* __restrict__ W1,
    const float* __restrict__ b3, const float* __restrict__ W5,
    const float* __restrict__ W6, const float* __restrict__ b5,
    unsigned short* __restrict__ W3B, unsigned short* __restrict__ W4T,
    float* __restrict__ partB,
    float* __restrict__ C34, float* __restrict__ W56, float* __restrict__ C56){
  __shared__ int   sdeg[V_];
  __shared__ int   srp[V_ + 1];
  __shared__ int   sfill[V_];
  __shared__ float sdinv[V_];
  __shared__ float swsum[V_];
  __shared__ float sw2[V_];
  __shared__ int   swt[16];
  __shared__ __align__(16) float tile[4][32][33];
  if (blockIdx.x == 0){
    const int t = threadIdx.x;
    sdeg[2*t] = 0; sdeg[2*t+1] = 0; sfill[2*t] = 0; sfill[2*t+1] = 0;
    __syncthreads();
    #pragma unroll
    for (int e = t; e < E_; e += 1024) atomicAdd(&sdeg[ei[E_ + e]], 1);
    __syncthreads();
    int c0 = sdeg[2*t], c1 = sdeg[2*t+1];
    int s2 = c0 + c1;
    int lane = t & 63, wid = t >> 6;
    int pre = s2;
    #pragma unroll
    for (int off = 1; off < 64; off <<= 1){
      int u = __shfl_up(pre, off);
      if (lane >= off) pre += u;
    }
    if (lane == 63) swt[wid] = pre;
    __syncthreads();
    if (t == 0){
      int run = 0;
      #pragma unroll
      for (int i = 0; i < 16; i++){ int x = swt[i]; swt[i] = run; run += x; }
      srp[V_] = run;
    }
    __syncthreads();
    int base = swt[wid] + (pre - s2);
    srp[2*t] = base; srp[2*t+1] = base + c0;
    #pragma unroll
    for (int v = t; v < V_; v += 1024){
      float d = (float)(sdeg[v] + 1);
      float di = rsqrtf(d);
      sdinv[v] = di;
      swsum[v] = di * di;
    }
    __syncthreads();
    #pragma unroll
    for (int e = t; e < E_; e += 1024){
      int s = ei[e], d = ei[E_ + e];
      int pos = srp[d] + atomicAdd(&sfill[d], 1);
      float val = sdinv[s] * sdinv[d];
      cols_g[pos] = s;
      vals_g[pos] = val;
      atomicAdd(&swsum[d], val);
    }
    __syncthreads();
    #pragma unroll
    for (int v = t; v < V_; v += 1024)
      sw2[v] = (sdinv[v] * sdinv[v]) * swsum[v];
    __syncthreads();
    #pragma unroll
    for (int e = t; e < E_; e += 1024){
      int s = ei[e], d = ei[E_ + e];
      atomicAdd(&sw2[d], sdinv[s] * sdinv[d] * swsum[s]);
    }
    __syncthreads();
    #pragma unroll
    for (int v = t; v < V_; v += 1024){
      rowptr_g[v] = srp[v];
      selfw_g[v]  = sdinv[v] * sdinv[v];
      wsum_g[v]   = swsum[v];
      w2_g[v]     = sw2[v];
    }
    if (t == 0) rowptr_g[V_] = srp[V_];
  } else {
    int u = blockIdx.x - 1;
    int t10 = threadIdx.x;
    int sub = (u << 2) + (t10 >> 8);
    int t = t10 & 255;
    int ti = t10 >> 8;
    if (sub < 256){
      int tr0 = (sub >> 4) << 5, tc0 = (sub & 15) << 5;
      int r = t >> 5, c = t & 31;
      #pragma unroll
      for (int i = 0; i < 4; i++)
        tile[ti][r + 8*i][c] = W4[(size_t)(tr0 + r + 8*i) * 512 + tc0 + c];
      __syncthreads();
      #pragma unroll
      for (int i = 0; i < 4; i++)
        W4T[(size_t)(tc0 + r + 8*i) * 512 + tr0 + c] = f2bf(tile[ti][c][r + 8*i]);
    } else if (sub < 256 + 1024){
      int id = (sub - 256) * 256 + t;
      W3B[id] = f2bf(W3[id]);
    } else if (sub < 1344){
      // I1 partial GEMM: g in [0,64): kc = g>>1 (32 k-chunks of 16), nh = g&1
      int g = sub - 1280;
      int kc = g >> 1, nh = g & 1;
      int k0 = kc * 16;
      float* xs = &tile[ti][0][0];            // 512 floats, 16B-aligned slice
      for (int i = t; i < 512; i += 256)
        xs[i] = img[(size_t)(i >> 4) * 512 + k0 + (i & 15)];
      __syncthreads();
      const float* W = W1 + 3 * 512;
      int n = (nh << 8) + t;
      float acc[32] = {};
      #pragma unroll
      for (int kg = 0; kg < 4; kg++){
        const float* wp = W + (size_t)(k0 + kg * 4) * 512 + n;
        float w0 = wp[0], w1 = wp[512], w2 = wp[1024], w3 = wp[1536];
        #pragma unroll
        for (int r = 0; r < 32; r++){
          f32x4 xv = *(const f32x4*)&xs[r * 16 + kg * 4];
          acc[r] += xv[0]*w0 + xv[1]*w1 + xv[2]*w2 + xv[3]*w3;
        }
      }
      float* p = partB + (size_t)kc * 16384 + n;
      #pragma unroll
      for (int r = 0; r < 32; r++) p[(size_t)r * 512] = acc[r];
    } else if (sub < 1346){
      // C34 = b3 . W4  (512 outputs)
      int id = (sub - 1344) * 256 + t;
      float a0=0,a1=0,a2=0,a3=0;
      for (int k = 0; k < 512; k += 4){
        a0 += b3[k]   * W4[(size_t)k * 512 + id];
        a1 += b3[k+1] * W4[(size_t)(k+1) * 512 + id];
        a2 += b3[k+2] * W4[(size_t)(k+2) * 512 + id];
        a3 += b3[k+3] * W4[(size_t)(k+3) * 512 + id];
      }
      C34[id] = a0+a1+a2+a3;
    } else if (sub < 1352){
      // W56 = W5 @ W6  (512x3 = 1536 outputs)
      int i = (sub - 1346) * 256 + t;
      int k5 = i / 3, j = i % 3;
      float a = 0.f;
      #pragma unroll 4
      for (int uu = 0; uu < 64; uu++) a += W5[k5 * 64 + uu] * W6[uu * 3 + j];
      W56[i] = a;
    } else if (sub == 1352){
      if (t < 3){
        float a = 0.f;
        #pragma unroll 4
        for (int uu = 0; uu < 64; uu++) a += b5[uu] * W6[uu * 3 + t];
        C56[t] = a;
      }
    }
  }
}

// ---------------- preC: P split-K partials (32x16 chunks); sums the 32 I1-partials INLINE ----------------
// (absorbs old k_preB's I1 reduce; writes to a disjoint partOut region to avoid overlap with partIn)
__global__ __launch_bounds__(256) void k_preC(
    const float* __restrict__ b1, const float* __restrict__ W1,
    const float* __restrict__ W2,
    const float* __restrict__ partIn, float* __restrict__ partOut){
  __shared__ __align__(16) float xs[36 * 16];
  int g = blockIdx.x;               // 64 blocks: kc = g>>1, nh = g&1
  int kc = g >> 1, k0 = kc * 16;
  int t = threadIdx.x;
  int n = ((g & 1) << 8) + t;
  for (int i = t; i < 576; i += 256){
    int r = i >> 4, kk = i & 15;
    float val;
    if (r == 0)      val = b1[k0 + kk];
    else if (r < 4)  val = W1[(size_t)(r - 1) * 512 + k0 + kk];
    else {
      float a = 0.f;
      #pragma unroll
      for (int s = 0; s < 32; s++)
        a += partIn[(size_t)s * 16384 + (size_t)(r - 4) * 512 + k0 + kk];
      val = a;
    }
    xs[i] = val;
  }
  __syncthreads();
  float acc[36] = {};
  #pragma unroll
  for (int kg = 0; kg < 4; kg++){
    const float* wp = W2 + (size_t)(k0 + kg * 4) * 512 + n;
    float w0 = wp[0], w1 = wp[512], w2 = wp[1024], w3 = wp[1536];
    #pragma unroll
    for (int r = 0; r < 36; r++){
      f32x4 xv = *(const f32x4*)&xs[r * 16 + kg * 4];
      acc[r] += xv[0]*w0 + xv[1]*w1 + xv[2]*w2 + xv[3]*w3;
    }
  }
  float* p = partOut + (size_t)kc * 18432 + n;
  #pragma unroll
  for (int r = 0; r < 36; r++) p[(size_t)r * 512] = acc[r];
}

// ---------------- preD: P reduce (32 partials) ----------------
__global__ __launch_bounds__(256) void k_preD(
    const float* __restrict__ partB, float* __restrict__ P){
  int id = blockIdx.x * 256 + threadIdx.x;
  float a = 0.f;
  #pragma unroll
  for (int s = 0; s < 32; s++) a += partB[(size_t)s * 18432 + id];
  P[id] = a;
}

// ---------------- k_va2a / k_va2b: A^2 on vertices, split into 2 kernels x 256 blocks ----------------
__global__ __launch_bounds__(256) void k_va2a(
    const float* __restrict__ in, const int* __restrict__ rowptr,
    const int* __restrict__ cols, const float* __restrict__ vals,
    const float* __restrict__ selfw, float* __restrict__ yout){
  __shared__ float xs[V_ * 3];
  int b = blockIdx.y, t = threadIdx.x;
  const float* ib = in + (size_t)b * V_ * 3;
  for (int i = t; i < V_ * 3; i += 256) xs[i] = ib[i];
  __syncthreads();
  int v = blockIdx.x * 256 + t;
  float sw = selfw[v];
  float a0 = sw * xs[v*3], a1 = sw * xs[v*3+1], a2 = sw * xs[v*3+2];
  int re = rowptr[v + 1];
  for (int e = rowptr[v]; e < re; e++){
    int s = cols[e]; float vv = vals[e];
    a0 += vv * xs[s*3]; a1 += vv * xs[s*3+1]; a2 += vv * xs[s*3+2];
  }
  float* o = yout + (size_t)b * V_ * 3 + v * 3;
  o[0] = a0; o[1] = a1; o[2] = a2;
}

__global__ __launch_bounds__(256) void k_va2b(
    const float* __restrict__ yin, const int* __restrict__ rowptr,
    const int* __restrict__ cols, const float* __restrict__ vals,
    const float* __restrict__ selfw, float* __restrict__ outv){
  __shared__ float xs[V_ * 3];
  int b = blockIdx.y, t = threadIdx.x;
  const float* ib = yin + (size_t)b * V_ * 3;
  for (int i = t; i < V_ * 3; i += 256) xs[i] = ib[i];
  __syncthreads();
  int v = blockIdx.x * 256 + t;
  float sw = selfw[v];
  float a0 = sw * xs[v*3], a1 = sw * xs[v*3+1], a2 = sw * xs[v*3+2];
  int re = rowptr[v + 1];
  for (int e = rowptr[v]; e < re; e++){
    int s = cols[e]; float vv = vals[e];
    a0 += vv * xs[s*3]; a1 += vv * xs[s*3+1]; a2 += vv * xs[s*3+2];
  }
  float* o = outv + ((size_t)v * 32 + b) * 3;
  o[0] = a0; o[1] = a1; o[2] = a2;
}

// ---------------- k_x2: layer-2 transform, computed ONCE per (v,b,f). H bf16 vertex-major ----------------
__global__ __launch_bounds__(1024) void k_x2(
    const float* __restrict__ va2v, const float* __restrict__ P,
    const float* __restrict__ wsum, const float* __restrict__ w2s,
    const float* __restrict__ b2,
    unsigned short* __restrict__ Y){
  int v = (blockIdx.x << 2) + (threadIdx.x >> 8);
  int batch = (blockIdx.y << 2) + ((threadIdx.x >> 6) & 3);
  int f8 = (threadIdx.x & 63) * 8;
  const float* va = va2v + ((size_t)v * 32 + batch) * 3;
  float x0 = va[0], x1 = va[1], x2 = va[2];
  float w2v = w2s[v], wsv = wsum[v];
  float tt[8];
  #pragma unroll
  for (int h = 0; h < 2; h++){
    f32x4 wv0 = *(const f32x4*)&P[512  + f8 + 4*h];
    f32x4 wv1 = *(const f32x4*)&P[1024 + f8 + 4*h];
    f32x4 wv2 = *(const f32x4*)&P[1536 + f8 + 4*h];
    f32x4 ccv = *(const f32x4*)&P[f8 + 4*h];
    f32x4 bbv = *(const f32x4*)&b2[f8 + 4*h];
    f32x4 iiv = *(const f32x4*)&P[2048 + (size_t)batch * 512 + f8 + 4*h];
    #pragma unroll
    for (int j = 0; j < 4; j++){
      float tv = x0*wv0[j] + x1*wv1[j] + x2*wv2[j] + w2v*iiv[j] + wsv*ccv[j] + bbv[j];
      tt[4*h + j] = fmaxf(tv, 0.f);
    }
  }
  unsigned int o[4];
  #pragma unroll
  for (int i = 0; i < 4; i++)
    o[i] = (unsigned int)f2bf(tt[2*i]) | ((unsigned int)f2bf(tt[2*i+1]) << 16);
  *(uint4*)&Y[((size_t)v * 32 + batch) * 512 + f8] = *(uint4*)o;
}

// ---------------- k_aggv: F=512 bf16 A-hop (proven 74us/hop = gather ceiling) ----------------
// r2 LDS-gather / r3 4MB-slice / r4 NT-store / r8 1MB-phase all failed to beat this;
// 470MB/74us = 6.3 TB/s -- at the measured gather rate. CLOSED.
__global__ __launch_bounds__(128) void k_aggv(
    const unsigned short* __restrict__ Hg, const int* __restrict__ rowptr,
    const int* __restrict__ cols, const float* __restrict__ vals,
    const float* __restrict__ selfw, unsigned short* __restrict__ Xo){
  int bid = blockIdx.x;
  int bg  = bid & 7;
  int dst = (bid >> 3) & (V_ - 1);
  int fc  = bid >> 14;
  int t = threadIdx.x;
  int batch = (bg << 2) + (t >> 5);
  int f8 = (fc << 8) + (t & 31) * 8;
  int rs = rowptr[dst], re = rowptr[dst + 1];
  float sw = selfw[dst];
  float a[8];
  {
    uint4 q = *(const uint4*)&Hg[((size_t)dst * 32 + batch) * 512 + f8];
    const unsigned int* w = (const unsigned int*)&q;
    #pragma unroll
    for (int i = 0; i < 4; i++){
      a[2*i]   = sw * bf2f(w[i] & 0xffff);
      a[2*i+1] = sw * bf2f(w[i] >> 16);
    }
  }
  int e = rs;
  for (; e + 1 < re; e += 2){
    int s0 = cols[e], s1 = cols[e+1];
    float v0 = vals[e], v1 = vals[e+1];
    uint4 q0 = *(const uint4*)&Hg[((size_t)s0 * 32 + batch) * 512 + f8];
    uint4 q1 = *(const uint4*)&Hg[((size_t)s1 * 32 + batch) * 512 + f8];
    const unsigned int* w0 = (const unsigned int*)&q0;
    const unsigned int* w1 = (const unsigned int*)&q1;
    #pragma unroll
    for (int i = 0; i < 4; i++){
      a[2*i]   += v0 * bf2f(w0[i] & 0xffff) + v1 * bf2f(w1[i] & 0xffff);
      a[2*i+1] += v0 * bf2f(w0[i] >> 16)    + v1 * bf2f(w1[i] >> 16);
    }
  }
  if (e < re){
    int s = cols[e]; float v = vals[e];
    uint4 q = *(const uint4*)&Hg[((size_t)s * 32 + batch) * 512 + f8];
    const unsigned int* w = (const unsigned int*)&q;
    #pragma unroll
    for (int i = 0; i < 4; i++){
      a[2*i]   += v * bf2f(w[i] & 0xffff);
      a[2*i+1] += v * bf2f(w[i] >> 16);
    }
  }
  unsigned int o[4];
  #pragma unroll
  for (int i = 0; i < 4; i++)
    o[i] = (unsigned int)f2bf(a[2*i]) | ((unsigned int)f2bf(a[2*i+1]) << 16);
  *(uint4*)&Xo[((size_t)dst * 32 + batch) * 512 + f8] = *(uint4*)o;
}

// ---------------- bf16 MFMA GEMM, A/B dbuf via global_load_lds, 1 barrier/iter ----------------
template<int BM, int BN, int WM, int WN, int TM, int TN>
__global__ __launch_bounds__(WM*WN*64) void k_gemm(
    const unsigned short* __restrict__ Xg, const unsigned short* __restrict__ Wt,
    unsigned short* __restrict__ Hg, int K, int N,
    const float* __restrict__ wsumv, const float* __restrict__ cvec,
    const float* __restrict__ bias, int relu,
    const float* __restrict__ W56g, float* __restrict__ h5p){
  constexpr int BK = 32;
  constexpr int NW = WM * WN;
  constexpr int NT = NW * 64;
  constexpr int RA = BM / NW;
  constexpr int RB = BN / NW;
  __shared__ __align__(16) unsigned short As[2][BM * BK];
  __shared__ __align__(16) unsigned short Bs[2][BN * BK];
  __shared__ float h5s[BM * 3];
  const int tid = threadIdx.x;
  const int row0 = blockIdx.x * BM, col0 = blockIdx.y * BN;
  const int wave = tid >> 6, lane = tid & 63;
  const int wr = wave / WN, wc = wave % WN;
  const int lrow = lane & 15, lq = lane >> 4;
  const int lrw = lane >> 2, lcol = (lane & 3) * 8;
  const int arow = wave * RA, brow = wave * RB;
  if (h5p){
    for (int i = tid; i < BM * 3; i += NT) h5s[i] = 0.f;
  }
  f32x4 acc[TM][TN] = {};
  #pragma unroll
  for (int t = 0; t < RA / 16; t++)
    gload16(&Xg[(size_t)(row0 + arow + t * 16 + lrw) * K + lcol],
            &As[0][(arow + t * 16) * BK]);
  #pragma unroll
  for (int t = 0; t < RB / 16; t++)
    gload16(&Wt[(size_t)(col0 + brow + t * 16 + lrw) * K + lcol],
            &Bs[0][(brow + t * 16) * BK]);
  int cur = 0;
  for (int k0 = 0; k0 < K; k0 += BK){
    __syncthreads();
    if (k0 + BK < K){
      #pragma unroll
      for (int t = 0; t < RA / 16; t++)
        gload16(&Xg[(size_t)(row0 + arow + t * 16 + lrw) * K + k0 + BK + lcol],
                &As[cur ^ 1][(arow + t * 16) * BK]);
      #pragma unroll
      for (int t = 0; t < RB / 16; t++)
        gload16(&Wt[(size_t)(col0 + brow + t * 16 + lrw) * K + k0 + BK + lcol],
                &Bs[cur ^ 1][(brow + t * 16) * BK]);
    }
    bf16x8 af[TM], bfr[TN];
    #pragma unroll
    for (int tm = 0; tm < TM; tm++)
      af[tm] = *(const bf16x8*)&As[cur][(wr * TM * 16 + tm * 16 + lrow) * BK + lq * 8];
    #pragma unroll
    for (int tn = 0; tn < TN; tn++)
      bfr[tn] = *(const bf16x8*)&Bs[cur][(wc * TN * 16 + tn * 16 + lrow) * BK + lq * 8];
    #pragma unroll
    for (int tm = 0; tm < TM; tm++)
      #pragma unroll
      for (int tn = 0; tn < TN; tn++)
        acc[tm][tn] = __builtin_amdgcn_mfma_f32_16x16x32_bf16(af[tm], bfr[tn], acc[tm][tn], 0, 0, 0);
    cur ^= 1;
  }
  if (h5p){
    // fused epilogue: relu(acc + wsum*cv + bv) . W56-slice -> block partial
    float w56l[TN][3], cvl[TN], bvl[TN];
    #pragma unroll
    for (int tn = 0; tn < TN; tn++){
      int col = col0 + wc * TN * 16 + tn * 16 + lrow;
      cvl[tn] = cvec[col]; bvl[tn] = bias[col];
      w56l[tn][0] = W56g[col * 3];
      w56l[tn][1] = W56g[col * 3 + 1];
      w56l[tn][2] = W56g[col * 3 + 2];
    }
    #pragma unroll
    for (int tm = 0; tm < TM; tm++){
      #pragma unroll
      for (int r = 0; r < 4; r++){
        int lr = wr * TM * 16 + tm * 16 + lq * 4 + r;
        float ws = wsumv[(row0 + lr) >> 5];
        float p0 = 0.f, p1 = 0.f, p2 = 0.f;
        #pragma unroll
        for (int tn = 0; tn < TN; tn++){
          float x = fmaxf(acc[tm][tn][r] + ws * cvl[tn] + bvl[tn], 0.f);
          p0 += x * w56l[tn][0]; p1 += x * w56l[tn][1]; p2 += x * w56l[tn][2];
        }
        #pragma unroll
        for (int off = 8; off; off >>= 1){
          p0 += __shfl_down(p0, off);
          p1 += __shfl_down(p1, off);
          p2 += __shfl_down(p2, off);
        }
        if (lrow == 0){
          atomicAdd(&h5s[lr * 3 + 0], p0);
          atomicAdd(&h5s[lr * 3 + 1], p1);
          atomicAdd(&h5s[lr * 3 + 2], p2);
        }
      }
    }
    __syncthreads();
    float* dst = h5p + (size_t)blockIdx.y * ((size_t)M_ * 3) + (size_t)row0 * 3;
    for (int i = tid; i < BM * 3; i += NT) dst[i] = h5s[i];
  } else {
    #pragma unroll
    for (int tm = 0; tm < TM; tm++){
      #pragma unroll
      for (int tn = 0; tn < TN; tn++){
        int col = col0 + wc * TN * 16 + tn * 16 + lrow;
        float cv = 0.f, bv = 0.f;
        if (cvec){ cv = cvec[col]; bv = bias[col]; }
        #pragma unroll
        for (int r = 0; r < 4; r++){
          int row = row0 + wr * TM * 16 + tm * 16 + lq * 4 + r;
          float x = acc[tm][tn][r];
          if (cvec) x += wsumv[row >> 5] * cv + bv;
          if (relu) x = fmaxf(x, 0.f);
          Hg[(size_t)row * N + col] = f2bf(x);
        }
      }
    }
  }
}

// ---------------- k_xa2a / k_xa2b: layers 5+6 tail split into 2 kernels x 256 blocks ----------------
__global__ __launch_bounds__(256) void k_xa2a(
    const float* __restrict__ h5p, const int* __restrict__ rowptr,
    const int* __restrict__ cols, const float* __restrict__ vals,
    const float* __restrict__ selfw, float* __restrict__ yout){
  __shared__ float xs[V_ * 3];
  int b = blockIdx.y, t = threadIdx.x;
  const size_t M3 = (size_t)M_ * 3;
  for (int i = t; i < V_ * 3; i += 256){
    int v = i / 3, j = i - v * 3;
    size_t g = ((size_t)v * 32 + b) * 3 + j;
    xs[i] = h5p[g] + h5p[M3 + g] + h5p[2 * M3 + g] + h5p[3 * M3 + g];
  }
  __syncthreads();
  int v = blockIdx.x * 256 + t;
  float sw = selfw[v];
  float a0 = sw * xs[v*3], a1 = sw * xs[v*3+1], a2 = sw * xs[v*3+2];
  int re = rowptr[v + 1];
  for (int e = rowptr[v]; e < re; e++){
    int s = cols[e]; float vv = vals[e];
    a0 += vv * xs[s*3]; a1 += vv * xs[s*3+1]; a2 += vv * xs[s*3+2];
  }
  float* o = yout + (size_t)b * V_ * 3 + v * 3;
  o[0] = a0; o[1] = a1; o[2] = a2;
}

__global__ __launch_bounds__(256) void k_xa2b(
    const float* __restrict__ yin, const int* __restrict__ rowptr,
    const int* __restrict__ cols, const float* __restrict__ vals,
    const float* __restrict__ selfw, const float* __restrict__ wsum,
    const float* __restrict__ C56, const float* __restrict__ b6,
    float* __restrict__ XF){
  __shared__ float xs[V_ * 3];
  int b = blockIdx.y, t = threadIdx.x;
  const float* ib = yin + (size_t)b * V_ * 3;
  for (int i = t; i < V_ * 3; i += 256) xs[i] = ib[i];
  __syncthreads();
  int v = blockIdx.x * 256 + t;
  float sw = selfw[v];
  float a0 = sw * xs[v*3], a1 = sw * xs[v*3+1], a2 = sw * xs[v*3+2];
  int re = rowptr[v + 1];
  for (int e = rowptr[v]; e < re; e++){
    int s = cols[e]; float vv = vals[e];
    a0 += vv * xs[s*3]; a1 += vv * xs[s*3+1]; a2 += vv * xs[s*3+2];
  }
  float w = wsum[v];
  a0 = fmaxf(a0 + w * C56[0] + b6[0], 0.f);
  a1 = fmaxf(a1 + w * C56[1] + b6[1], 0.f);
  a2 = fmaxf(a2 + w * C56[2] + b6[2], 0.f);
  float* ob = XF + (size_t)b * V_ * 3 + v * 3;
  ob[0] = a0; ob[1] = a1; ob[2] = a2;
}

// ---------------- FC split-K stage A ----------------
template<int R, int KC>
__global__ __launch_bounds__(256) void k_fcp(
    const float* __restrict__ in, const float* __restrict__ W,
    float* __restrict__ partial, int K, int N){
  const int n = blockIdx.x * 256 + threadIdx.x;
  const int k0 = blockIdx.y * KC;
  float acc[R] = {};
  for (int kk = 0; kk < KC; kk += 4){
    const float* wp = W + (size_t)(k0 + kk) * N + n;
    float w0 = wp[0];
    float w1 = wp[(size_t)N];
    float w2 = wp[(size_t)2 * N];
    float w3 = wp[(size_t)3 * N];
    #pragma unroll
    for (int r = 0; r < R; r++){
      const float* xp = in + (size_t)r * K + k0 + kk;
      acc[r] += xp[0]*w0 + xp[1]*w1 + xp[2]*w2 + xp[3]*w3;
    }
  }
  float* p = partial + (size_t)blockIdx.y * R * N + n;
  #pragma unroll
  for (int r = 0; r < R; r++) p[(size_t)r * N] = acc[r];
}

// ---------------- FC split-K stage B ----------------
__global__ __launch_bounds__(256) void k_fcr(
    const float* __restrict__ partial, const float* __restrict__ bias,
    float* __restrict__ out, int total, int N, int KS, int mode,
    const float* __restrict__ vert){
  int id = blockIdx.x * 256 + threadIdx.x;
  if (id >= total) return;
  int n = id % N;
  float a0 = 0.f, a1 = 0.f, a2 = 0.f, a3 = 0.f;
  int s = 0;
  for (; s + 4 <= KS; s += 4){
    a0 += partial[(size_t)s * total + id];
    a1 += partial[(size_t)(s + 1) * total + id];
    a2 += partial[(size_t)(s + 2) * total + id];
    a3 += partial[(size_t)(s + 3) * total + id];
  }
  for (; s < KS; s++) a0 += partial[(size_t)s * total + id];
  float acc = a0 + a1 + a2 + a3;
  if (bias) acc += bias[n];
  if (mode) acc = vert[id] + 0.1f * tanhf(acc);
  out[id] = acc;
}

// ---------------- workspace layout ----------------
static constexpr size_t AL(size_t x){ return (x + 255) & ~(size_t)255; }
static constexpr size_t S512 = (size_t)M_ * 512 * 2;
static constexpr size_t S3   = (size_t)M_ * 3 * 4;
static constexpr size_t OXA  = 0;
static constexpr size_t OXB  = OXA  + AL(S512);
static constexpr size_t OVA2 = OXB  + AL(S512);
static constexpr size_t OH5P = OVA2 + AL(S3);
static constexpr size_t OXF  = OH5P + AL(4 * S3);
static constexpr size_t OFC1 = OXF  + AL(S3);
static constexpr size_t OFC2 = OFC1 + AL((size_t)B_ * 1024 * 4);
static constexpr size_t OI1  = OFC2 + AL((size_t)B_ * 1024 * 4);
static constexpr size_t OP   = OI1  + AL((size_t)32 * 512 * 4);
static constexpr size_t OC34 = OP   + AL((size_t)36 * 512 * 4);
static constexpr size_t OW56 = OC34 + AL((size_t)512 * 4);
static constexpr size_t OC56 = OW56 + AL((size_t)512 * 3 * 4);
static constexpr size_t OW3B = OC56 + AL((size_t)3 * 4);
static constexpr size_t OW4T = OW3B + AL((size_t)512 * 512 * 2);
static constexpr size_t OW34 = OW4T + AL((size_t)512 * 512 * 2);
static constexpr size_t OROW = OW34 + AL((size_t)512 * 512 * 2);
static constexpr size_t OCOL = OROW + AL((size_t)(V_ + 1) * 4);
static constexpr size_t OVAL = OCOL + AL((size_t)E_ * 4);
static constexpr size_t OSELF= OVAL + AL((size_t)E_ * 4);
static constexpr size_t OWS  = OSELF+ AL((size_t)V_ * 4);
static constexpr size_t OW2S = OWS  + AL((size_t)V_ * 4);

extern "C" void kernel_launch(void* const* d_in, const int* in_sizes, int n_in,
                              void* d_out, int out_size, void* d_ws, size_t ws_size,
                              hipStream_t stream){
  const float* vert  = (const float*)d_in[0];
  const float* img   = (const float*)d_in[1];
  const int*   ei    = (const int*)  d_in[2];
  const float* W1 = (const float*)d_in[3],  *b1 = (const float*)d_in[4];
  const float* W2 = (const float*)d_in[5],  *b2 = (const float*)d_in[6];
  const float* W3 = (const float*)d_in[7],  *b3 = (const float*)d_in[8];
  const float* W4 = (const float*)d_in[9],  *b4 = (const float*)d_in[10];
  const float* W5 = (const float*)d_in[11], *b5 = (const float*)d_in[12];
  const float* W6 = (const float*)d_in[13], *b6 = (const float*)d_in[14];
  const float* fcW1 = (const float*)d_in[15], *fcb1 = (const float*)d_in[16];
  const float* fcW2 = (const float*)d_in[17], *fcb2 = (const float*)d_in[18];
  const float* fcW3 = (const float*)d_in[19], *fcb3 = (const float*)d_in[20];
  float* out = (float*)d_out;

  char* ws = (char*)d_ws;
  unsigned short* XA  = (unsigned short*)(ws + OXA);
  unsigned short* XB  = (unsigned short*)(ws + OXB);
  float* VA2v = (float*)(ws + OVA2);
  float* H5P  = (float*)(ws + OH5P);
  float* XF   = (float*)(ws + OXF);
  float* FC1o = (float*)(ws + OFC1);
  float* FC2o = (float*)(ws + OFC2);
  float* P    = (float*)(ws + OP);
  float* C34  = (float*)(ws + OC34);
  float* W56  = (float*)(ws + OW56);
  float* C56  = (float*)(ws + OC56);
  unsigned short* W3B = (unsigned short*)(ws + OW3B);
  unsigned short* W4T = (unsigned short*)(ws + OW4T);
  unsigned short* W34 = (unsigned short*)(ws + OW34);
  float* PARTA = (float*)(ws + OXA);
  float* PARTB = (float*)(ws + OXB);
  float* PARTC = (float*)(ws + OXB) + (1 << 20);   // preC output, disjoint from I1 partials
  float* YTMP  = (float*)(ws + OXA);   // hop intermediate; OXA region idle at those points
  int*   ROW  = (int*)(ws + OROW);
  int*   COL  = (int*)(ws + OCOL);
  float* VAL  = (float*)(ws + OVAL);
  float* SELF = (float*)(ws + OSELF);
  float* WSUM = (float*)(ws + OWS);
  float* W2S  = (float*)(ws + OW2S);

  // ---- CSR (block 0) + preA (blocks 1..339, incl. folded C34/W56/C56) ----
  k_pre0<<<340, 1024, 0, stream>>>(ei, ROW, COL, VAL, SELF, WSUM, W2S,
                                   W3, W4, img, W1, b3, W5, W6, b5,
                                   W3B, W4T, PARTB, C34, W56, C56);
  k_preC<<<64, 256, 0, stream>>>(b1, W1, W2, PARTB, PARTC);
  k_preD<<<72, 256, 0, stream>>>(PARTC, P);
  k_gemm<64,64,2,2,2,2><<<dim3(8, 8), 256, 0, stream>>>(W4T, W3B, W34, 512, 512,
                                                        nullptr, nullptr, nullptr, 0,
                                                        nullptr, nullptr);

  // ---- layers 1-2: VA2 split (2 x 256 blocks), transform once (k_x2), two A-hops ----
  k_va2a<<<dim3(8, B_), 256, 0, stream>>>(vert, ROW, COL, VAL, SELF, YTMP);
  k_va2b<<<dim3(8, B_), 256, 0, stream>>>(YTMP, ROW, COL, VAL, SELF, VA2v);
  k_x2<<<dim3(V_ / 4, 8), 1024, 0, stream>>>(VA2v, P, WSUM, W2S, b2, XA);
  k_aggv<<<V_ * 16, 128, 0, stream>>>(XA, ROW, COL, VAL, SELF, XB);
  k_aggv<<<V_ * 16, 128, 0, stream>>>(XB, ROW, COL, VAL, SELF, XA);

  // ---- GEMM w/ fused epilogue AND fused W56 contraction ----
  k_gemm<128,128,2,2,4,4><<<dim3(M_ / 128, 4), 256, 0, stream>>>(XA, W34, XB, 512, 512,
                                                                 WSUM, C34, b4, 1,
                                                                 W56, H5P);

  // ---- layers 5+6 tail: split A^2 (F=3) + epilogue, 2 x 256 blocks ----
  k_xa2a<<<dim3(8, B_), 256, 0, stream>>>(H5P, ROW, COL, VAL, SELF, YTMP);
  k_xa2b<<<dim3(8, B_), 256, 0, stream>>>(YTMP, ROW, COL, VAL, SELF, WSUM, C56, b6, XF);

  // ---- FC head ----
  k_fcp<32,64><<<dim3(4, 96), 256, 0, stream>>>(XF, fcW1, PARTA, 6144, 1024);
  k_fcr<<<(B_ * 1024 + 255) / 256, 256, 0, stream>>>(PARTA, fcb1, FC1o, 32 * 1024, 1024, 96, 0, nullptr);
  k_fcp<32,64><<<dim3(4, 16), 256, 0, stream>>>(FC1o, fcW2, PARTA, 1024, 1024);
  k_fcr<<<(B_ * 1024 + 255) / 256, 256, 0, stream>>>(PARTA, fcb2, FC2o, 32 * 1024, 1024, 16, 0, nullptr);
  k_fcp<32,64><<<dim3(24, 16), 256, 0, stream>>>(FC2o, fcW3, PARTA, 1024, 6144);
  k_fcr<<<(B_ * 6144 + 255) / 256, 256, 0, stream>>>(PARTA, fcb3, out, 32 * 6144, 6144, 16, 1, vert);
}

// Round 10
// 493.214 us; speedup vs baseline: 1.1967x; 1.0100x over previous
//
#include <hip/hip_runtime.h>
#include <stdint.h>
#include <math.h>

#define B_ 32
#define V_ 2048
#define E_ 12288
#define M_ (B_*V_)

typedef __bf16 bf16x8 __attribute__((ext_vector_type(8)));
typedef float f32x4 __attribute__((ext_vector_type(4)));

__device__ __forceinline__ float bf2f(unsigned short u){
  union { unsigned int i; float f; } v; v.i = ((unsigned int)u) << 16; return v.f;
}
__device__ __forceinline__ unsigned short f2bf(float f){
  union { float f; unsigned int i; } v; v.f = f;
  unsigned int r = (v.i + 0x7fffu + ((v.i >> 16) & 1u)) >> 16;
  return (unsigned short)r;
}
__device__ __forceinline__ void gload16(const unsigned short* g, unsigned short* l){
  __builtin_amdgcn_global_load_lds(
      (const __attribute__((address_space(1))) void*)g,
      (__attribute__((address_space(3))) void*)l, 16, 0, 0);
}

// ---------------- k_pre0: block 0 = CSR build (1024 thr); blocks 1.. = preA work ----------------
__global__ __launch_bounds__(1024) void k_pre0(
    const int* __restrict__ ei, int* __restrict__ rowptr_g, int* __restrict__ cols_g,
    float* __restrict__ vals_g, float* __restrict__ selfw_g,
    float* __restrict__ wsum_g, float* __restrict__ w2_g,
    const float* __restrict__ W3, const float* __restrict__ W4,
    const float* __restrict__ img, const float* __restrict__ W1,
    const float* __restrict__ b3, const float* __restrict__ W5,
    const float* __restrict__ W6, const float* __restrict__ b5,
    unsigned short* __restrict__ W3B, unsigned short* __restrict__ W4T,
    float* __restrict__ partB,
    float* __restrict__ C34, float* __restrict__ W56, float* __restrict__ C56){
  __shared__ int   sdeg[V_];
  __shared__ int   srp[V_ + 1];
  __shared__ int   sfill[V_];
  __shared__ float sdinv[V_];
  __shared__ float swsum[V_];
  __shared__ float sw2[V_];
  __shared__ int   swt[16];
  __shared__ __align__(16) float tile[4][32][33];
  if (blockIdx.x == 0){
    const int t = threadIdx.x;
    sdeg[2*t] = 0; sdeg[2*t+1] = 0; sfill[2*t] = 0; sfill[2*t+1] = 0;
    __syncthreads();
    #pragma unroll
    for (int e = t; e < E_; e += 1024) atomicAdd(&sdeg[ei[E_ + e]], 1);
    __syncthreads();
    int c0 = sdeg[2*t], c1 = sdeg[2*t+1];
    int s2 = c0 + c1;
    int lane = t & 63, wid = t >> 6;
    int pre = s2;
    #pragma unroll
    for (int off = 1; off < 64; off <<= 1){
      int u = __shfl_up(pre, off);
      if (lane >= off) pre += u;
    }
    if (lane == 63) swt[wid] = pre;
    __syncthreads();
    if (t == 0){
      int run = 0;
      #pragma unroll
      for (int i = 0; i < 16; i++){ int x = swt[i]; swt[i] = run; run += x; }
      srp[V_] = run;
    }
    __syncthreads();
    int base = swt[wid] + (pre - s2);
    srp[2*t] = base; srp[2*t+1] = base + c0;
    #pragma unroll
    for (int v = t; v < V_; v += 1024){
      float d = (float)(sdeg[v] + 1);
      float di = rsqrtf(d);
      sdinv[v] = di;
      swsum[v] = di * di;
    }
    __syncthreads();
    #pragma unroll
    for (int e = t; e < E_; e += 1024){
      int s = ei[e], d = ei[E_ + e];
      int pos = srp[d] + atomicAdd(&sfill[d], 1);
      float val = sdinv[s] * sdinv[d];
      cols_g[pos] = s;
      vals_g[pos] = val;
      atomicAdd(&swsum[d], val);
    }
    __syncthreads();
    #pragma unroll
    for (int v = t; v < V_; v += 1024)
      sw2[v] = (sdinv[v] * sdinv[v]) * swsum[v];
    __syncthreads();
    #pragma unroll
    for (int e = t; e < E_; e += 1024){
      int s = ei[e], d = ei[E_ + e];
      atomicAdd(&sw2[d], sdinv[s] * sdinv[d] * swsum[s]);
    }
    __syncthreads();
    #pragma unroll
    for (int v = t; v < V_; v += 1024){
      rowptr_g[v] = srp[v];
      selfw_g[v]  = sdinv[v] * sdinv[v];
      wsum_g[v]   = swsum[v];
      w2_g[v]     = sw2[v];
    }
    if (t == 0) rowptr_g[V_] = srp[V_];
  } else {
    int u = blockIdx.x - 1;
    int t10 = threadIdx.x;
    int sub = (u << 2) + (t10 >> 8);
    int t = t10 & 255;
    int ti = t10 >> 8;
    if (sub < 256){
      int tr0 = (sub >> 4) << 5, tc0 = (sub & 15) << 5;
      int r = t >> 5, c = t & 31;
      #pragma unroll
      for (int i = 0; i < 4; i++)
        tile[ti][r + 8*i][c] = W4[(size_t)(tr0 + r + 8*i) * 512 + tc0 + c];
      __syncthreads();
      #pragma unroll
      for (int i = 0; i < 4; i++)
        W4T[(size_t)(tc0 + r + 8*i) * 512 + tr0 + c] = f2bf(tile[ti][c][r + 8*i]);
    } else if (sub < 256 + 1024){
      int id = (sub - 256) * 256 + t;
      W3B[id] = f2bf(W3[id]);
    } else if (sub < 1344){
      int g = sub - 1280;
      int kc = g >> 1, nh = g & 1;
      int k0 = kc * 16;
      float* xs = &tile[ti][0][0];
      for (int i = t; i < 512; i += 256)
        xs[i] = img[(size_t)(i >> 4) * 512 + k0 + (i & 15)];
      __syncthreads();
      const float* W = W1 + 3 * 512;
      int n = (nh << 8) + t;
      float acc[32] = {};
      #pragma unroll
      for (int kg = 0; kg < 4; kg++){
        const float* wp = W + (size_t)(k0 + kg * 4) * 512 + n;
        float w0 = wp[0], w1 = wp[512], w2 = wp[1024], w3 = wp[1536];
        #pragma unroll
        for (int r = 0; r < 32; r++){
          f32x4 xv = *(const f32x4*)&xs[r * 16 + kg * 4];
          acc[r] += xv[0]*w0 + xv[1]*w1 + xv[2]*w2 + xv[3]*w3;
        }
      }
      float* p = partB + (size_t)kc * 16384 + n;
      #pragma unroll
      for (int r = 0; r < 32; r++) p[(size_t)r * 512] = acc[r];
    } else if (sub < 1346){
      int id = (sub - 1344) * 256 + t;
      float a0=0,a1=0,a2=0,a3=0;
      for (int k = 0; k < 512; k += 4){
        a0 += b3[k]   * W4[(size_t)k * 512 + id];
        a1 += b3[k+1] * W4[(size_t)(k+1) * 512 + id];
        a2 += b3[k+2] * W4[(size_t)(k+2) * 512 + id];
        a3 += b3[k+3] * W4[(size_t)(k+3) * 512 + id];
      }
      C34[id] = a0+a1+a2+a3;
    } else if (sub < 1352){
      int i = (sub - 1346) * 256 + t;
      int k5 = i / 3, j = i % 3;
      float a = 0.f;
      #pragma unroll 4
      for (int uu = 0; uu < 64; uu++) a += W5[k5 * 64 + uu] * W6[uu * 3 + j];
      W56[i] = a;
    } else if (sub == 1352){
      if (t < 3){
        float a = 0.f;
        #pragma unroll 4
        for (int uu = 0; uu < 64; uu++) a += b5[uu] * W6[uu * 3 + t];
        C56[t] = a;
      }
    }
  }
}

// ---------------- shared GEMM body (used by big k_gemm and the W34 product in k_mix1) ----------------
template<int BM, int BN, int WM, int WN, int TM, int TN>
__device__ __forceinline__ void gemm_body(
    int bx, int by,
    const unsigned short* __restrict__ Xg, const unsigned short* __restrict__ Wt,
    unsigned short* __restrict__ Hg, int K, int N,
    const float* __restrict__ wsumv, const float* __restrict__ cvec,
    const float* __restrict__ bias, int relu,
    const float* __restrict__ W56g, float* __restrict__ h5p){
  constexpr int BK = 32;
  constexpr int NW = WM * WN;
  constexpr int NT = NW * 64;
  constexpr int RA = BM / NW;
  constexpr int RB = BN / NW;
  __shared__ __align__(16) unsigned short As[2][BM * BK];
  __shared__ __align__(16) unsigned short Bs[2][BN * BK];
  __shared__ float h5s[BM * 3];
  const int tid = threadIdx.x;
  const int row0 = bx * BM, col0 = by * BN;
  const int wave = tid >> 6, lane = tid & 63;
  const int wr = wave / WN, wc = wave % WN;
  const int lrow = lane & 15, lq = lane >> 4;
  const int lrw = lane >> 2, lcol = (lane & 3) * 8;
  const int arow = wave * RA, brow = wave * RB;
  if (h5p){
    for (int i = tid; i < BM * 3; i += NT) h5s[i] = 0.f;
  }
  f32x4 acc[TM][TN] = {};
  #pragma unroll
  for (int t = 0; t < RA / 16; t++)
    gload16(&Xg[(size_t)(row0 + arow + t * 16 + lrw) * K + lcol],
            &As[0][(arow + t * 16) * BK]);
  #pragma unroll
  for (int t = 0; t < RB / 16; t++)
    gload16(&Wt[(size_t)(col0 + brow + t * 16 + lrw) * K + lcol],
            &Bs[0][(brow + t * 16) * BK]);
  int cur = 0;
  for (int k0 = 0; k0 < K; k0 += BK){
    __syncthreads();
    if (k0 + BK < K){
      #pragma unroll
      for (int t = 0; t < RA / 16; t++)
        gload16(&Xg[(size_t)(row0 + arow + t * 16 + lrw) * K + k0 + BK + lcol],
                &As[cur ^ 1][(arow + t * 16) * BK]);
      #pragma unroll
      for (int t = 0; t < RB / 16; t++)
        gload16(&Wt[(size_t)(col0 + brow + t * 16 + lrw) * K + k0 + BK + lcol],
                &Bs[cur ^ 1][(brow + t * 16) * BK]);
    }
    bf16x8 af[TM], bfr[TN];
    #pragma unroll
    for (int tm = 0; tm < TM; tm++)
      af[tm] = *(const bf16x8*)&As[cur][(wr * TM * 16 + tm * 16 + lrow) * BK + lq * 8];
    #pragma unroll
    for (int tn = 0; tn < TN; tn++)
      bfr[tn] = *(const bf16x8*)&Bs[cur][(wc * TN * 16 + tn * 16 + lrow) * BK + lq * 8];
    #pragma unroll
    for (int tm = 0; tm < TM; tm++)
      #pragma unroll
      for (int tn = 0; tn < TN; tn++)
        acc[tm][tn] = __builtin_amdgcn_mfma_f32_16x16x32_bf16(af[tm], bfr[tn], acc[tm][tn], 0, 0, 0);
    cur ^= 1;
  }
  if (h5p){
    float w56l[TN][3], cvl[TN], bvl[TN];
    #pragma unroll
    for (int tn = 0; tn < TN; tn++){
      int col = col0 + wc * TN * 16 + tn * 16 + lrow;
      cvl[tn] = cvec[col]; bvl[tn] = bias[col];
      w56l[tn][0] = W56g[col * 3];
      w56l[tn][1] = W56g[col * 3 + 1];
      w56l[tn][2] = W56g[col * 3 + 2];
    }
    #pragma unroll
    for (int tm = 0; tm < TM; tm++){
      #pragma unroll
      for (int r = 0; r < 4; r++){
        int lr = wr * TM * 16 + tm * 16 + lq * 4 + r;
        float ws = wsumv[(row0 + lr) >> 5];
        float p0 = 0.f, p1 = 0.f, p2 = 0.f;
        #pragma unroll
        for (int tn = 0; tn < TN; tn++){
          float x = fmaxf(acc[tm][tn][r] + ws * cvl[tn] + bvl[tn], 0.f);
          p0 += x * w56l[tn][0]; p1 += x * w56l[tn][1]; p2 += x * w56l[tn][2];
        }
        #pragma unroll
        for (int off = 8; off; off >>= 1){
          p0 += __shfl_down(p0, off);
          p1 += __shfl_down(p1, off);
          p2 += __shfl_down(p2, off);
        }
        if (lrow == 0){
          atomicAdd(&h5s[lr * 3 + 0], p0);
          atomicAdd(&h5s[lr * 3 + 1], p1);
          atomicAdd(&h5s[lr * 3 + 2], p2);
        }
      }
    }
    __syncthreads();
    float* dst = h5p + (size_t)by * ((size_t)M_ * 3) + (size_t)row0 * 3;
    for (int i = tid; i < BM * 3; i += NT) dst[i] = h5s[i];
  } else {
    #pragma unroll
    for (int tm = 0; tm < TM; tm++){
      #pragma unroll
      for (int tn = 0; tn < TN; tn++){
        int col = col0 + wc * TN * 16 + tn * 16 + lrow;
        float cv = 0.f, bv = 0.f;
        if (cvec){ cv = cvec[col]; bv = bias[col]; }
        #pragma unroll
        for (int r = 0; r < 4; r++){
          int row = row0 + wr * TM * 16 + tm * 16 + lq * 4 + r;
          float x = acc[tm][tn][r];
          if (cvec) x += wsumv[row >> 5] * cv + bv;
          if (relu) x = fmaxf(x, 0.f);
          Hg[(size_t)row * N + col] = f2bf(x);
        }
      }
    }
  }
}

template<int BM, int BN, int WM, int WN, int TM, int TN>
__global__ __launch_bounds__(WM*WN*64) void k_gemm(
    const unsigned short* __restrict__ Xg, const unsigned short* __restrict__ Wt,
    unsigned short* __restrict__ Hg, int K, int N,
    const float* __restrict__ wsumv, const float* __restrict__ cvec,
    const float* __restrict__ bias, int relu,
    const float* __restrict__ W56g, float* __restrict__ h5p){
  gemm_body<BM,BN,WM,WN,TM,TN>(blockIdx.x, blockIdx.y, Xg, Wt, Hg, K, N,
                               wsumv, cvec, bias, relu, W56g, h5p);
}

// ---------------- device bodies for the fused mid-chain ----------------
// preC: P split-K partials, sums the 32 I1 partials inline during staging.
__device__ __forceinline__ void preC_body(
    int g, const float* __restrict__ b1, const float* __restrict__ W1,
    const float* __restrict__ W2,
    const float* __restrict__ partIn, float* __restrict__ partOut){
  __shared__ __align__(16) float xs[36 * 16];
  int kc = g >> 1, k0 = kc * 16;
  int t = threadIdx.x;
  int n = ((g & 1) << 8) + t;
  for (int i = t; i < 576; i += 256){
    int r = i >> 4, kk = i & 15;
    float val;
    if (r == 0)      val = b1[k0 + kk];
    else if (r < 4)  val = W1[(size_t)(r - 1) * 512 + k0 + kk];
    else {
      float a = 0.f;
      #pragma unroll
      for (int s = 0; s < 32; s++)
        a += partIn[(size_t)s * 16384 + (size_t)(r - 4) * 512 + k0 + kk];
      val = a;
    }
    xs[i] = val;
  }
  __syncthreads();
  float acc[36] = {};
  #pragma unroll
  for (int kg = 0; kg < 4; kg++){
    const float* wp = W2 + (size_t)(k0 + kg * 4) * 512 + n;
    float w0 = wp[0], w1 = wp[512], w2 = wp[1024], w3 = wp[1536];
    #pragma unroll
    for (int r = 0; r < 36; r++){
      f32x4 xv = *(const f32x4*)&xs[r * 16 + kg * 4];
      acc[r] += xv[0]*w0 + xv[1]*w1 + xv[2]*w2 + xv[3]*w3;
    }
  }
  float* p = partOut + (size_t)kc * 18432 + n;
  #pragma unroll
  for (int r = 0; r < 36; r++) p[(size_t)r * 512] = acc[r];
}

// va2 hop: stages full per-batch x (24KB), each thread handles one dst.
// out_vmajor=0 -> yout[b][v*3]; out_vmajor=1 -> outv[(v*32+b)*3]
__device__ __forceinline__ void va2_body(
    int bx, int b, const float* __restrict__ in, const int* __restrict__ rowptr,
    const int* __restrict__ cols, const float* __restrict__ vals,
    const float* __restrict__ selfw, float* __restrict__ outp, int out_vmajor){
  __shared__ float xs[V_ * 3];
  int t = threadIdx.x;
  const float* ib = in + (size_t)b * V_ * 3;
  for (int i = t; i < V_ * 3; i += 256) xs[i] = ib[i];
  __syncthreads();
  int v = bx * 256 + t;
  float sw = selfw[v];
  float a0 = sw * xs[v*3], a1 = sw * xs[v*3+1], a2 = sw * xs[v*3+2];
  int re = rowptr[v + 1];
  for (int e = rowptr[v]; e < re; e++){
    int s = cols[e]; float vv = vals[e];
    a0 += vv * xs[s*3]; a1 += vv * xs[s*3+1]; a2 += vv * xs[s*3+2];
  }
  float* o = out_vmajor ? (outp + ((size_t)v * 32 + b) * 3)
                        : (outp + (size_t)b * V_ * 3 + (size_t)v * 3);
  o[0] = a0; o[1] = a1; o[2] = a2;
}

// ---------------- k_mix1: blocks [0,64) W34 gemm | [64,128) preC | [128,384) va2a ----------------
__global__ __launch_bounds__(256) void k_mix1(
    const unsigned short* __restrict__ W4T, const unsigned short* __restrict__ W3B,
    unsigned short* __restrict__ W34,
    const float* __restrict__ b1, const float* __restrict__ W1,
    const float* __restrict__ W2,
    const float* __restrict__ partIn, float* __restrict__ partOut,
    const float* __restrict__ vert, const int* __restrict__ rowptr,
    const int* __restrict__ cols, const float* __restrict__ vals,
    const float* __restrict__ selfw, float* __restrict__ ytmp){
  int blk = blockIdx.x;
  if (blk < 64){
    gemm_body<64,64,2,2,2,2>(blk & 7, blk >> 3, W4T, W3B, W34, 512, 512,
                             nullptr, nullptr, nullptr, 0, nullptr, nullptr);
  } else if (blk < 128){
    preC_body(blk - 64, b1, W1, W2, partIn, partOut);
  } else {
    int r = blk - 128;
    va2_body(r & 7, r >> 3, vert, rowptr, cols, vals, selfw, ytmp, 0);
  }
}

// ---------------- k_mix2: blocks [0,72) preD | [72,328) va2b ----------------
__global__ __launch_bounds__(256) void k_mix2(
    const float* __restrict__ partC, float* __restrict__ P,
    const float* __restrict__ ytmp, const int* __restrict__ rowptr,
    const int* __restrict__ cols, const float* __restrict__ vals,
    const float* __restrict__ selfw, float* __restrict__ va2v){
  int blk = blockIdx.x;
  if (blk < 72){
    int id = blk * 256 + threadIdx.x;
    float a = 0.f;
    #pragma unroll
    for (int s = 0; s < 32; s++) a += partC[(size_t)s * 18432 + id];
    P[id] = a;
  } else {
    int r = blk - 72;
    va2_body(r & 7, r >> 3, ytmp, rowptr, cols, vals, selfw, va2v, 1);
  }
}

// ---------------- k_y1: fused x2-on-the-fly + A-hop (proven 80us in r0/r1). ----------------
// Fused form beats split x2(14)+aggv(74)=88 since aggv is at the gather ceiling.
__global__ __launch_bounds__(256) void k_y1(
    const float* __restrict__ va2v, const float* __restrict__ P,
    const float* __restrict__ wsum, const float* __restrict__ w2s,
    const float* __restrict__ b2,
    const int* __restrict__ rowptr, const int* __restrict__ cols,
    const float* __restrict__ vals, const float* __restrict__ selfw,
    unsigned short* __restrict__ Y){
  int dst = blockIdx.x;
  int batch = (blockIdx.y << 2) + (threadIdx.x >> 6);
  int f8 = (threadIdx.x & 63) * 8;
  float wv0[8], wv1[8], wv2[8], cc[8], bb[8], ii[8];
  #pragma unroll
  for (int j = 0; j < 8; j++){
    int fc = f8 + j;
    wv0[j] = P[512 + fc]; wv1[j] = P[1024 + fc]; wv2[j] = P[1536 + fc];
    cc[j]  = P[fc];       bb[j]  = b2[fc];
    ii[j]  = P[2048 + (size_t)batch * 512 + fc];
  }
  float acc[8] = {};
  int rs = rowptr[dst], re = rowptr[dst + 1];
  for (int e = rs - 1; e < re; e++){
    int s; float w;
    if (e < rs){ s = dst; w = selfw[dst]; }
    else       { s = cols[e]; w = vals[e]; }
    const float* va = va2v + ((size_t)s * 32 + batch) * 3;
    float x0 = va[0], x1 = va[1], x2 = va[2];
    float w2v = w2s[s], wsv = wsum[s];
    #pragma unroll
    for (int j = 0; j < 8; j++){
      float tv = x0*wv0[j] + x1*wv1[j] + x2*wv2[j] + w2v*ii[j] + wsv*cc[j] + bb[j];
      tv = fmaxf(tv, 0.f);
      acc[j] += w * tv;
    }
  }
  unsigned int o[4];
  #pragma unroll
  for (int i = 0; i < 4; i++)
    o[i] = (unsigned int)f2bf(acc[2*i]) | ((unsigned int)f2bf(acc[2*i+1]) << 16);
  *(uint4*)&Y[((size_t)dst * 32 + batch) * 512 + f8] = *(uint4*)o;
}

// ---------------- k_aggv: F=512 bf16 A-hop (proven 74us/hop = gather ceiling; CLOSED) ----------------
__global__ __launch_bounds__(128) void k_aggv(
    const unsigned short* __restrict__ Hg, const int* __restrict__ rowptr,
    const int* __restrict__ cols, const float* __restrict__ vals,
    const float* __restrict__ selfw, unsigned short* __restrict__ Xo){
  int bid = blockIdx.x;
  int bg  = bid & 7;
  int dst = (bid >> 3) & (V_ - 1);
  int fc  = bid >> 14;
  int t = threadIdx.x;
  int batch = (bg << 2) + (t >> 5);
  int f8 = (fc << 8) + (t & 31) * 8;
  int rs = rowptr[dst], re = rowptr[dst + 1];
  float sw = selfw[dst];
  float a[8];
  {
    uint4 q = *(const uint4*)&Hg[((size_t)dst * 32 + batch) * 512 + f8];
    const unsigned int* w = (const unsigned int*)&q;
    #pragma unroll
    for (int i = 0; i < 4; i++){
      a[2*i]   = sw * bf2f(w[i] & 0xffff);
      a[2*i+1] = sw * bf2f(w[i] >> 16);
    }
  }
  int e = rs;
  for (; e + 1 < re; e += 2){
    int s0 = cols[e], s1 = cols[e+1];
    float v0 = vals[e], v1 = vals[e+1];
    uint4 q0 = *(const uint4*)&Hg[((size_t)s0 * 32 + batch) * 512 + f8];
    uint4 q1 = *(const uint4*)&Hg[((size_t)s1 * 32 + batch) * 512 + f8];
    const unsigned int* w0 = (const unsigned int*)&q0;
    const unsigned int* w1 = (const unsigned int*)&q1;
    #pragma unroll
    for (int i = 0; i < 4; i++){
      a[2*i]   += v0 * bf2f(w0[i] & 0xffff) + v1 * bf2f(w1[i] & 0xffff);
      a[2*i+1] += v0 * bf2f(w0[i] >> 16)    + v1 * bf2f(w1[i] >> 16);
    }
  }
  if (e < re){
    int s = cols[e]; float v = vals[e];
    uint4 q = *(const uint4*)&Hg[((size_t)s * 32 + batch) * 512 + f8];
    const unsigned int* w = (const unsigned int*)&q;
    #pragma unroll
    for (int i = 0; i < 4; i++){
      a[2*i]   += v * bf2f(w[i] & 0xffff);
      a[2*i+1] += v * bf2f(w[i] >> 16);
    }
  }
  unsigned int o[4];
  #pragma unroll
  for (int i = 0; i < 4; i++)
    o[i] = (unsigned int)f2bf(a[2*i]) | ((unsigned int)f2bf(a[2*i+1]) << 16);
  *(uint4*)&Xo[((size_t)dst * 32 + batch) * 512 + f8] = *(uint4*)o;
}

// ---------------- k_xa2a / k_xa2b: layers 5+6 tail split into 2 kernels x 256 blocks ----------------
__global__ __launch_bounds__(256) void k_xa2a(
    const float* __restrict__ h5p, const int* __restrict__ rowptr,
    const int* __restrict__ cols, const float* __restrict__ vals,
    const float* __restrict__ selfw, float* __restrict__ yout){
  __shared__ float xs[V_ * 3];
  int b = blockIdx.y, t = threadIdx.x;
  const size_t M3 = (size_t)M_ * 3;
  for (int i = t; i < V_ * 3; i += 256){
    int v = i / 3, j = i - v * 3;
    size_t g = ((size_t)v * 32 + b) * 3 + j;
    xs[i] = h5p[g] + h5p[M3 + g] + h5p[2 * M3 + g] + h5p[3 * M3 + g];
  }
  __syncthreads();
  int v = blockIdx.x * 256 + t;
  float sw = selfw[v];
  float a0 = sw * xs[v*3], a1 = sw * xs[v*3+1], a2 = sw * xs[v*3+2];
  int re = rowptr[v + 1];
  for (int e = rowptr[v]; e < re; e++){
    int s = cols[e]; float vv = vals[e];
    a0 += vv * xs[s*3]; a1 += vv * xs[s*3+1]; a2 += vv * xs[s*3+2];
  }
  float* o = yout + (size_t)b * V_ * 3 + v * 3;
  o[0] = a0; o[1] = a1; o[2] = a2;
}

__global__ __launch_bounds__(256) void k_xa2b(
    const float* __restrict__ yin, const int* __restrict__ rowptr,
    const int* __restrict__ cols, const float* __restrict__ vals,
    const float* __restrict__ selfw, const float* __restrict__ wsum,
    const float* __restrict__ C56, const float* __restrict__ b6,
    float* __restrict__ XF){
  __shared__ float xs[V_ * 3];
  int b = blockIdx.y, t = threadIdx.x;
  const float* ib = yin + (size_t)b * V_ * 3;
  for (int i = t; i < V_ * 3; i += 256) xs[i] = ib[i];
  __syncthreads();
  int v = blockIdx.x * 256 + t;
  float sw = selfw[v];
  float a0 = sw * xs[v*3], a1 = sw * xs[v*3+1], a2 = sw * xs[v*3+2];
  int re = rowptr[v + 1];
  for (int e = rowptr[v]; e < re; e++){
    int s = cols[e]; float vv = vals[e];
    a0 += vv * xs[s*3]; a1 += vv * xs[s*3+1]; a2 += vv * xs[s*3+2];
  }
  float w = wsum[v];
  a0 = fmaxf(a0 + w * C56[0] + b6[0], 0.f);
  a1 = fmaxf(a1 + w * C56[1] + b6[1], 0.f);
  a2 = fmaxf(a2 + w * C56[2] + b6[2], 0.f);
  float* ob = XF + (size_t)b * V_ * 3 + v * 3;
  ob[0] = a0; ob[1] = a1; ob[2] = a2;
}

// ---------------- FC split-K stage A ----------------
template<int R, int KC>
__global__ __launch_bounds__(256) void k_fcp(
    const float* __restrict__ in, const float* __restrict__ W,
    float* __restrict__ partial, int K, int N){
  const int n = blockIdx.x * 256 + threadIdx.x;
  const int k0 = blockIdx.y * KC;
  float acc[R] = {};
  for (int kk = 0; kk < KC; kk += 4){
    const float* wp = W + (size_t)(k0 + kk) * N + n;
    float w0 = wp[0];
    float w1 = wp[(size_t)N];
    float w2 = wp[(size_t)2 * N];
    float w3 = wp[(size_t)3 * N];
    #pragma unroll
    for (int r = 0; r < R; r++){
      const float* xp = in + (size_t)r * K + k0 + kk;
      acc[r] += xp[0]*w0 + xp[1]*w1 + xp[2]*w2 + xp[3]*w3;
    }
  }
  float* p = partial + (size_t)blockIdx.y * R * N + n;
  #pragma unroll
  for (int r = 0; r < R; r++) p[(size_t)r * N] = acc[r];
}

// ---------------- FC split-K stage B ----------------
__global__ __launch_bounds__(256) void k_fcr(
    const float* __restrict__ partial, const float* __restrict__ bias,
    float* __restrict__ out, int total, int N, int KS, int mode,
    const float* __restrict__ vert){
  int id = blockIdx.x * 256 + threadIdx.x;
  if (id >= total) return;
  int n = id % N;
  float a0 = 0.f, a1 = 0.f, a2 = 0.f, a3 = 0.f;
  int s = 0;
  for (; s + 4 <= KS; s += 4){
    a0 += partial[(size_t)s * total + id];
    a1 += partial[(size_t)(s + 1) * total + id];
    a2 += partial[(size_t)(s + 2) * total + id];
    a3 += partial[(size_t)(s + 3) * total + id];
  }
  for (; s < KS; s++) a0 += partial[(size_t)s * total + id];
  float acc = a0 + a1 + a2 + a3;
  if (bias) acc += bias[n];
  if (mode) acc = vert[id] + 0.1f * tanhf(acc);
  out[id] = acc;
}

// ---------------- workspace layout ----------------
static constexpr size_t AL(size_t x){ return (x + 255) & ~(size_t)255; }
static constexpr size_t S512 = (size_t)M_ * 512 * 2;
static constexpr size_t S3   = (size_t)M_ * 3 * 4;
static constexpr size_t OXA  = 0;
static constexpr size_t OXB  = OXA  + AL(S512);
static constexpr size_t OVA2 = OXB  + AL(S512);
static constexpr size_t OH5P = OVA2 + AL(S3);
static constexpr size_t OXF  = OH5P + AL(4 * S3);
static constexpr size_t OFC1 = OXF  + AL(S3);
static constexpr size_t OFC2 = OFC1 + AL((size_t)B_ * 1024 * 4);
static constexpr size_t OI1  = OFC2 + AL((size_t)B_ * 1024 * 4);
static constexpr size_t OP   = OI1  + AL((size_t)32 * 512 * 4);
static constexpr size_t OC34 = OP   + AL((size_t)36 * 512 * 4);
static constexpr size_t OW56 = OC34 + AL((size_t)512 * 4);
static constexpr size_t OC56 = OW56 + AL((size_t)512 * 3 * 4);
static constexpr size_t OW3B = OC56 + AL((size_t)3 * 4);
static constexpr size_t OW4T = OW3B + AL((size_t)512 * 512 * 2);
static constexpr size_t OW34 = OW4T + AL((size_t)512 * 512 * 2);
static constexpr size_t OROW = OW34 + AL((size_t)512 * 512 * 2);
static constexpr size_t OCOL = OROW + AL((size_t)(V_ + 1) * 4);
static constexpr size_t OVAL = OCOL + AL((size_t)E_ * 4);
static constexpr size_t OSELF= OVAL + AL((size_t)E_ * 4);
static constexpr size_t OWS  = OSELF+ AL((size_t)V_ * 4);
static constexpr size_t OW2S = OWS  + AL((size_t)V_ * 4);

extern "C" void kernel_launch(void* const* d_in, const int* in_sizes, int n_in,
                              void* d_out, int out_size, void* d_ws, size_t ws_size,
                              hipStream_t stream){
  const float* vert  = (const float*)d_in[0];
  const float* img   = (const float*)d_in[1];
  const int*   ei    = (const int*)  d_in[2];
  const float* W1 = (const float*)d_in[3],  *b1 = (const float*)d_in[4];
  const float* W2 = (const float*)d_in[5],  *b2 = (const float*)d_in[6];
  const float* W3 = (const float*)d_in[7],  *b3 = (const float*)d_in[8];
  const float* W4 = (const float*)d_in[9],  *b4 = (const float*)d_in[10];
  const float* W5 = (const float*)d_in[11], *b5 = (const float*)d_in[12];
  const float* W6 = (const float*)d_in[13], *b6 = (const float*)d_in[14];
  const float* fcW1 = (const float*)d_in[15], *fcb1 = (const float*)d_in[16];
  const float* fcW2 = (const float*)d_in[17], *fcb2 = (const float*)d_in[18];
  const float* fcW3 = (const float*)d_in[19], *fcb3 = (const float*)d_in[20];
  float* out = (float*)d_out;

  char* ws = (char*)d_ws;
  unsigned short* XA  = (unsigned short*)(ws + OXA);
  unsigned short* XB  = (unsigned short*)(ws + OXB);
  float* VA2v = (float*)(ws + OVA2);
  float* H5P  = (float*)(ws + OH5P);
  float* XF   = (float*)(ws + OXF);
  float* FC1o = (float*)(ws + OFC1);
  float* FC2o = (float*)(ws + OFC2);
  float* P    = (float*)(ws + OP);
  float* C34  = (float*)(ws + OC34);
  float* W56  = (float*)(ws + OW56);
  float* C56  = (float*)(ws + OC56);
  unsigned short* W3B = (unsigned short*)(ws + OW3B);
  unsigned short* W4T = (unsigned short*)(ws + OW4T);
  unsigned short* W34 = (unsigned short*)(ws + OW34);
  float* PARTA = (float*)(ws + OXA);
  float* PARTB = (float*)(ws + OXB);
  float* PARTC = (float*)(ws + OXB) + (1 << 20);   // preC output, disjoint from I1 partials
  float* YTMP  = (float*)(ws + OXA);   // hop intermediate; OXA region idle at those points
  int*   ROW  = (int*)(ws + OROW);
  int*   COL  = (int*)(ws + OCOL);
  float* VAL  = (float*)(ws + OVAL);
  float* SELF = (float*)(ws + OSELF);
  float* WSUM = (float*)(ws + OWS);
  float* W2S  = (float*)(ws + OW2S);

  // ---- CSR (block 0) + preA (blocks 1..339, incl. folded C34/W56/C56) ----
  k_pre0<<<340, 1024, 0, stream>>>(ei, ROW, COL, VAL, SELF, WSUM, W2S,
                                   W3, W4, img, W1, b3, W5, W6, b5,
                                   W3B, W4T, PARTB, C34, W56, C56);

  // ---- mix1: W34 gemm (64) + preC (64) + va2a (256) -- mutually independent ----
  k_mix1<<<384, 256, 0, stream>>>(W4T, W3B, W34, b1, W1, W2, PARTB, PARTC,
                                  vert, ROW, COL, VAL, SELF, YTMP);
  // ---- mix2: preD (72) + va2b (256) ----
  k_mix2<<<328, 256, 0, stream>>>(PARTC, P, YTMP, ROW, COL, VAL, SELF, VA2v);

  // ---- layer 2 transform fused with first A-hop (k_y1), then second hop ----
  k_y1<<<dim3(V_, 8), 256, 0, stream>>>(VA2v, P, WSUM, W2S, b2, ROW, COL, VAL, SELF, XB);
  k_aggv<<<V_ * 16, 128, 0, stream>>>(XB, ROW, COL, VAL, SELF, XA);

  // ---- GEMM w/ fused epilogue AND fused W56 contraction ----
  k_gemm<128,128,2,2,4,4><<<dim3(M_ / 128, 4), 256, 0, stream>>>(XA, W34, XB, 512, 512,
                                                                 WSUM, C34, b4, 1,
                                                                 W56, H5P);

  // ---- layers 5+6 tail: split A^2 (F=3) + epilogue, 2 x 256 blocks ----
  k_xa2a<<<dim3(8, B_), 256, 0, stream>>>(H5P, ROW, COL, VAL, SELF, YTMP);
  k_xa2b<<<dim3(8, B_), 256, 0, stream>>>(YTMP, ROW, COL, VAL, SELF, WSUM, C56, b6, XF);

  // ---- FC head ----
  k_fcp<32,64><<<dim3(4, 96), 256, 0, stream>>>(XF, fcW1, PARTA, 6144, 1024);
  k_fcr<<<(B_ * 1024 + 255) / 256, 256, 0, stream>>>(PARTA, fcb1, FC1o, 32 * 1024, 1024, 96, 0, nullptr);
  k_fcp<32,64><<<dim3(4, 16), 256, 0, stream>>>(FC1o, fcW2, PARTA, 1024, 1024);
  k_fcr<<<(B_ * 1024 + 255) / 256, 256, 0, stream>>>(PARTA, fcb2, FC2o, 32 * 1024, 1024, 16, 0, nullptr);
  k_fcp<32,64><<<dim3(24, 16), 256, 0, stream>>>(FC2o, fcW3, PARTA, 1024, 6144);
  k_fcr<<<(B_ * 6144 + 255) / 256, 256, 0, stream>>>(PARTA, fcb3, out, 32 * 6144, 6144, 16, 1, vert);
}

// Round 11
// 490.293 us; speedup vs baseline: 1.2038x; 1.0060x over previous
//
#include <hip/hip_runtime.h>
#include <stdint.h>
#include <math.h>

#define B_ 32
#define V_ 2048
#define E_ 12288
#define M_ (B_*V_)

typedef __bf16 bf16x8 __attribute__((ext_vector_type(8)));
typedef float f32x4 __attribute__((ext_vector_type(4)));

__device__ __forceinline__ float bf2f(unsigned short u){
  union { unsigned int i; float f; } v; v.i = ((unsigned int)u) << 16; return v.f;
}
__device__ __forceinline__ unsigned short f2bf(float f){
  union { float f; unsigned int i; } v; v.f = f;
  unsigned int r = (v.i + 0x7fffu + ((v.i >> 16) & 1u)) >> 16;
  return (unsigned short)r;
}
__device__ __forceinline__ void gload16(const unsigned short* g, unsigned short* l){
  __builtin_amdgcn_global_load_lds(
      (const __attribute__((address_space(1))) void*)g,
      (__attribute__((address_space(3))) void*)l, 16, 0, 0);
}

// ---------------- k_pre0: block 0 = CSR build (1024 thr); blocks 1.. = preA work ----------------
__global__ __launch_bounds__(1024) void k_pre0(
    const int* __restrict__ ei, int* __restrict__ rowptr_g, int* __restrict__ cols_g,
    float* __restrict__ vals_g, float* __restrict__ selfw_g,
    float* __restrict__ wsum_g, float* __restrict__ w2_g,
    const float* __restrict__ W3, const float* __restrict__ W4,
    const float* __restrict__ img, const float* __restrict__ W1,
    const float* __restrict__ b3, const float* __restrict__ W5,
    const float* __restrict__ W6, const float* __restrict__ b5,
    unsigned short* __restrict__ W3B, unsigned short* __restrict__ W4T,
    float* __restrict__ partB,
    float* __restrict__ C34, float* __restrict__ W56, float* __restrict__ C56){
  __shared__ int   sdeg[V_];
  __shared__ int   srp[V_ + 1];
  __shared__ int   sfill[V_];
  __shared__ float sdinv[V_];
  __shared__ float swsum[V_];
  __shared__ float sw2[V_];
  __shared__ int   swt[16];
  __shared__ __align__(16) float tile[4][32][33];
  if (blockIdx.x == 0){
    const int t = threadIdx.x;
    sdeg[2*t] = 0; sdeg[2*t+1] = 0; sfill[2*t] = 0; sfill[2*t+1] = 0;
    __syncthreads();
    #pragma unroll
    for (int e = t; e < E_; e += 1024) atomicAdd(&sdeg[ei[E_ + e]], 1);
    __syncthreads();
    int c0 = sdeg[2*t], c1 = sdeg[2*t+1];
    int s2 = c0 + c1;
    int lane = t & 63, wid = t >> 6;
    int pre = s2;
    #pragma unroll
    for (int off = 1; off < 64; off <<= 1){
      int u = __shfl_up(pre, off);
      if (lane >= off) pre += u;
    }
    if (lane == 63) swt[wid] = pre;
    __syncthreads();
    if (t == 0){
      int run = 0;
      #pragma unroll
      for (int i = 0; i < 16; i++){ int x = swt[i]; swt[i] = run; run += x; }
      srp[V_] = run;
    }
    __syncthreads();
    int base = swt[wid] + (pre - s2);
    srp[2*t] = base; srp[2*t+1] = base + c0;
    #pragma unroll
    for (int v = t; v < V_; v += 1024){
      float d = (float)(sdeg[v] + 1);
      float di = rsqrtf(d);
      sdinv[v] = di;
      swsum[v] = di * di;
    }
    __syncthreads();
    #pragma unroll
    for (int e = t; e < E_; e += 1024){
      int s = ei[e], d = ei[E_ + e];
      int pos = srp[d] + atomicAdd(&sfill[d], 1);
      float val = sdinv[s] * sdinv[d];
      cols_g[pos] = s;
      vals_g[pos] = val;
      atomicAdd(&swsum[d], val);
    }
    __syncthreads();
    #pragma unroll
    for (int v = t; v < V_; v += 1024)
      sw2[v] = (sdinv[v] * sdinv[v]) * swsum[v];
    __syncthreads();
    #pragma unroll
    for (int e = t; e < E_; e += 1024){
      int s = ei[e], d = ei[E_ + e];
      atomicAdd(&sw2[d], sdinv[s] * sdinv[d] * swsum[s]);
    }
    __syncthreads();
    #pragma unroll
    for (int v = t; v < V_; v += 1024){
      rowptr_g[v] = srp[v];
      selfw_g[v]  = sdinv[v] * sdinv[v];
      wsum_g[v]   = swsum[v];
      w2_g[v]     = sw2[v];
    }
    if (t == 0) rowptr_g[V_] = srp[V_];
  } else {
    int u = blockIdx.x - 1;
    int t10 = threadIdx.x;
    int sub = (u << 2) + (t10 >> 8);
    int t = t10 & 255;
    int ti = t10 >> 8;
    if (sub < 256){
      int tr0 = (sub >> 4) << 5, tc0 = (sub & 15) << 5;
      int r = t >> 5, c = t & 31;
      #pragma unroll
      for (int i = 0; i < 4; i++)
        tile[ti][r + 8*i][c] = W4[(size_t)(tr0 + r + 8*i) * 512 + tc0 + c];
      __syncthreads();
      #pragma unroll
      for (int i = 0; i < 4; i++)
        W4T[(size_t)(tc0 + r + 8*i) * 512 + tr0 + c] = f2bf(tile[ti][c][r + 8*i]);
    } else if (sub < 256 + 1024){
      int id = (sub - 256) * 256 + t;
      W3B[id] = f2bf(W3[id]);
    } else if (sub < 1344){
      int g = sub - 1280;
      int kc = g >> 1, nh = g & 1;
      int k0 = kc * 16;
      float* xs = &tile[ti][0][0];
      for (int i = t; i < 512; i += 256)
        xs[i] = img[(size_t)(i >> 4) * 512 + k0 + (i & 15)];
      __syncthreads();
      const float* W = W1 + 3 * 512;
      int n = (nh << 8) + t;
      float acc[32] = {};
      #pragma unroll
      for (int kg = 0; kg < 4; kg++){
        const float* wp = W + (size_t)(k0 + kg * 4) * 512 + n;
        float w0 = wp[0], w1 = wp[512], w2 = wp[1024], w3 = wp[1536];
        #pragma unroll
        for (int r = 0; r < 32; r++){
          f32x4 xv = *(const f32x4*)&xs[r * 16 + kg * 4];
          acc[r] += xv[0]*w0 + xv[1]*w1 + xv[2]*w2 + xv[3]*w3;
        }
      }
      float* p = partB + (size_t)kc * 16384 + n;
      #pragma unroll
      for (int r = 0; r < 32; r++) p[(size_t)r * 512] = acc[r];
    } else if (sub < 1346){
      int id = (sub - 1344) * 256 + t;
      float a0=0,a1=0,a2=0,a3=0;
      for (int k = 0; k < 512; k += 4){
        a0 += b3[k]   * W4[(size_t)k * 512 + id];
        a1 += b3[k+1] * W4[(size_t)(k+1) * 512 + id];
        a2 += b3[k+2] * W4[(size_t)(k+2) * 512 + id];
        a3 += b3[k+3] * W4[(size_t)(k+3) * 512 + id];
      }
      C34[id] = a0+a1+a2+a3;
    } else if (sub < 1352){
      int i = (sub - 1346) * 256 + t;
      int k5 = i / 3, j = i % 3;
      float a = 0.f;
      #pragma unroll 4
      for (int uu = 0; uu < 64; uu++) a += W5[k5 * 64 + uu] * W6[uu * 3 + j];
      W56[i] = a;
    } else if (sub == 1352){
      if (t < 3){
        float a = 0.f;
        #pragma unroll 4
        for (int uu = 0; uu < 64; uu++) a += b5[uu] * W6[uu * 3 + t];
        C56[t] = a;
      }
    }
  }
}

// ---------------- shared GEMM body (used by big k_gemm and the W34 product in k_mix1) ----------------
template<int BM, int BN, int WM, int WN, int TM, int TN>
__device__ __forceinline__ void gemm_body(
    int bx, int by,
    const unsigned short* __restrict__ Xg, const unsigned short* __restrict__ Wt,
    unsigned short* __restrict__ Hg, int K, int N,
    const float* __restrict__ wsumv, const float* __restrict__ cvec,
    const float* __restrict__ bias, int relu,
    const float* __restrict__ W56g, float* __restrict__ h5p){
  constexpr int BK = 32;
  constexpr int NW = WM * WN;
  constexpr int NT = NW * 64;
  constexpr int RA = BM / NW;
  constexpr int RB = BN / NW;
  __shared__ __align__(16) unsigned short As[2][BM * BK];
  __shared__ __align__(16) unsigned short Bs[2][BN * BK];
  __shared__ float h5s[BM * 3];
  const int tid = threadIdx.x;
  const int row0 = bx * BM, col0 = by * BN;
  const int wave = tid >> 6, lane = tid & 63;
  const int wr = wave / WN, wc = wave % WN;
  const int lrow = lane & 15, lq = lane >> 4;
  const int lrw = lane >> 2, lcol = (lane & 3) * 8;
  const int arow = wave * RA, brow = wave * RB;
  if (h5p){
    for (int i = tid; i < BM * 3; i += NT) h5s[i] = 0.f;
  }
  f32x4 acc[TM][TN] = {};
  #pragma unroll
  for (int t = 0; t < RA / 16; t++)
    gload16(&Xg[(size_t)(row0 + arow + t * 16 + lrw) * K + lcol],
            &As[0][(arow + t * 16) * BK]);
  #pragma unroll
  for (int t = 0; t < RB / 16; t++)
    gload16(&Wt[(size_t)(col0 + brow + t * 16 + lrw) * K + lcol],
            &Bs[0][(brow + t * 16) * BK]);
  int cur = 0;
  for (int k0 = 0; k0 < K; k0 += BK){
    __syncthreads();
    if (k0 + BK < K){
      #pragma unroll
      for (int t = 0; t < RA / 16; t++)
        gload16(&Xg[(size_t)(row0 + arow + t * 16 + lrw) * K + k0 + BK + lcol],
                &As[cur ^ 1][(arow + t * 16) * BK]);
      #pragma unroll
      for (int t = 0; t < RB / 16; t++)
        gload16(&Wt[(size_t)(col0 + brow + t * 16 + lrw) * K + k0 + BK + lcol],
                &Bs[cur ^ 1][(brow + t * 16) * BK]);
    }
    bf16x8 af[TM], bfr[TN];
    #pragma unroll
    for (int tm = 0; tm < TM; tm++)
      af[tm] = *(const bf16x8*)&As[cur][(wr * TM * 16 + tm * 16 + lrow) * BK + lq * 8];
    #pragma unroll
    for (int tn = 0; tn < TN; tn++)
      bfr[tn] = *(const bf16x8*)&Bs[cur][(wc * TN * 16 + tn * 16 + lrow) * BK + lq * 8];
    #pragma unroll
    for (int tm = 0; tm < TM; tm++)
      #pragma unroll
      for (int tn = 0; tn < TN; tn++)
        acc[tm][tn] = __builtin_amdgcn_mfma_f32_16x16x32_bf16(af[tm], bfr[tn], acc[tm][tn], 0, 0, 0);
    cur ^= 1;
  }
  if (h5p){
    float w56l[TN][3], cvl[TN], bvl[TN];
    #pragma unroll
    for (int tn = 0; tn < TN; tn++){
      int col = col0 + wc * TN * 16 + tn * 16 + lrow;
      cvl[tn] = cvec[col]; bvl[tn] = bias[col];
      w56l[tn][0] = W56g[col * 3];
      w56l[tn][1] = W56g[col * 3 + 1];
      w56l[tn][2] = W56g[col * 3 + 2];
    }
    #pragma unroll
    for (int tm = 0; tm < TM; tm++){
      #pragma unroll
      for (int r = 0; r < 4; r++){
        int lr = wr * TM * 16 + tm * 16 + lq * 4 + r;
        float ws = wsumv[(row0 + lr) >> 5];
        float p0 = 0.f, p1 = 0.f, p2 = 0.f;
        #pragma unroll
        for (int tn = 0; tn < TN; tn++){
          float x = fmaxf(acc[tm][tn][r] + ws * cvl[tn] + bvl[tn], 0.f);
          p0 += x * w56l[tn][0]; p1 += x * w56l[tn][1]; p2 += x * w56l[tn][2];
        }
        #pragma unroll
        for (int off = 8; off; off >>= 1){
          p0 += __shfl_down(p0, off);
          p1 += __shfl_down(p1, off);
          p2 += __shfl_down(p2, off);
        }
        if (lrow == 0){
          atomicAdd(&h5s[lr * 3 + 0], p0);
          atomicAdd(&h5s[lr * 3 + 1], p1);
          atomicAdd(&h5s[lr * 3 + 2], p2);
        }
      }
    }
    __syncthreads();
    float* dst = h5p + (size_t)by * ((size_t)M_ * 3) + (size_t)row0 * 3;
    for (int i = tid; i < BM * 3; i += NT) dst[i] = h5s[i];
  } else {
    #pragma unroll
    for (int tm = 0; tm < TM; tm++){
      #pragma unroll
      for (int tn = 0; tn < TN; tn++){
        int col = col0 + wc * TN * 16 + tn * 16 + lrow;
        float cv = 0.f, bv = 0.f;
        if (cvec){ cv = cvec[col]; bv = bias[col]; }
        #pragma unroll
        for (int r = 0; r < 4; r++){
          int row = row0 + wr * TM * 16 + tm * 16 + lq * 4 + r;
          float x = acc[tm][tn][r];
          if (cvec) x += wsumv[row >> 5] * cv + bv;
          if (relu) x = fmaxf(x, 0.f);
          Hg[(size_t)row * N + col] = f2bf(x);
        }
      }
    }
  }
}

template<int BM, int BN, int WM, int WN, int TM, int TN>
__global__ __launch_bounds__(WM*WN*64) void k_gemm(
    const unsigned short* __restrict__ Xg, const unsigned short* __restrict__ Wt,
    unsigned short* __restrict__ Hg, int K, int N,
    const float* __restrict__ wsumv, const float* __restrict__ cvec,
    const float* __restrict__ bias, int relu,
    const float* __restrict__ W56g, float* __restrict__ h5p){
  gemm_body<BM,BN,WM,WN,TM,TN>(blockIdx.x, blockIdx.y, Xg, Wt, Hg, K, N,
                               wsumv, cvec, bias, relu, W56g, h5p);
}

// ---------------- device bodies for the fused mid-chain ----------------
__device__ __forceinline__ void preC_body(
    int g, const float* __restrict__ b1, const float* __restrict__ W1,
    const float* __restrict__ W2,
    const float* __restrict__ partIn, float* __restrict__ partOut){
  __shared__ __align__(16) float xs[36 * 16];
  int kc = g >> 1, k0 = kc * 16;
  int t = threadIdx.x;
  int n = ((g & 1) << 8) + t;
  for (int i = t; i < 576; i += 256){
    int r = i >> 4, kk = i & 15;
    float val;
    if (r == 0)      val = b1[k0 + kk];
    else if (r < 4)  val = W1[(size_t)(r - 1) * 512 + k0 + kk];
    else {
      float a = 0.f;
      #pragma unroll
      for (int s = 0; s < 32; s++)
        a += partIn[(size_t)s * 16384 + (size_t)(r - 4) * 512 + k0 + kk];
      val = a;
    }
    xs[i] = val;
  }
  __syncthreads();
  float acc[36] = {};
  #pragma unroll
  for (int kg = 0; kg < 4; kg++){
    const float* wp = W2 + (size_t)(k0 + kg * 4) * 512 + n;
    float w0 = wp[0], w1 = wp[512], w2 = wp[1024], w3 = wp[1536];
    #pragma unroll
    for (int r = 0; r < 36; r++){
      f32x4 xv = *(const f32x4*)&xs[r * 16 + kg * 4];
      acc[r] += xv[0]*w0 + xv[1]*w1 + xv[2]*w2 + xv[3]*w3;
    }
  }
  float* p = partOut + (size_t)kc * 18432 + n;
  #pragma unroll
  for (int r = 0; r < 36; r++) p[(size_t)r * 512] = acc[r];
}

__device__ __forceinline__ void va2_body(
    int bx, int b, const float* __restrict__ in, const int* __restrict__ rowptr,
    const int* __restrict__ cols, const float* __restrict__ vals,
    const float* __restrict__ selfw, float* __restrict__ outp, int out_vmajor){
  __shared__ float xs[V_ * 3];
  int t = threadIdx.x;
  const float* ib = in + (size_t)b * V_ * 3;
  for (int i = t; i < V_ * 3; i += 256) xs[i] = ib[i];
  __syncthreads();
  int v = bx * 256 + t;
  float sw = selfw[v];
  float a0 = sw * xs[v*3], a1 = sw * xs[v*3+1], a2 = sw * xs[v*3+2];
  int re = rowptr[v + 1];
  for (int e = rowptr[v]; e < re; e++){
    int s = cols[e]; float vv = vals[e];
    a0 += vv * xs[s*3]; a1 += vv * xs[s*3+1]; a2 += vv * xs[s*3+2];
  }
  float* o = out_vmajor ? (outp + ((size_t)v * 32 + b) * 3)
                        : (outp + (size_t)b * V_ * 3 + (size_t)v * 3);
  o[0] = a0; o[1] = a1; o[2] = a2;
}

// ---------------- k_mix1: blocks [0,64) W34 gemm | [64,128) preC | [128,384) va2a ----------------
__global__ __launch_bounds__(256) void k_mix1(
    const unsigned short* __restrict__ W4T, const unsigned short* __restrict__ W3B,
    unsigned short* __restrict__ W34,
    const float* __restrict__ b1, const float* __restrict__ W1,
    const float* __restrict__ W2,
    const float* __restrict__ partIn, float* __restrict__ partOut,
    const float* __restrict__ vert, const int* __restrict__ rowptr,
    const int* __restrict__ cols, const float* __restrict__ vals,
    const float* __restrict__ selfw, float* __restrict__ ytmp){
  int blk = blockIdx.x;
  if (blk < 64){
    gemm_body<64,64,2,2,2,2>(blk & 7, blk >> 3, W4T, W3B, W34, 512, 512,
                             nullptr, nullptr, nullptr, 0, nullptr, nullptr);
  } else if (blk < 128){
    preC_body(blk - 64, b1, W1, W2, partIn, partOut);
  } else {
    int r = blk - 128;
    va2_body(r & 7, r >> 3, vert, rowptr, cols, vals, selfw, ytmp, 0);
  }
}

// ---------------- k_mix2: blocks [0,72) preD | [72,328) va2b ----------------
__global__ __launch_bounds__(256) void k_mix2(
    const float* __restrict__ partC, float* __restrict__ P,
    const float* __restrict__ ytmp, const int* __restrict__ rowptr,
    const int* __restrict__ cols, const float* __restrict__ vals,
    const float* __restrict__ selfw, float* __restrict__ va2v){
  int blk = blockIdx.x;
  if (blk < 72){
    int id = blk * 256 + threadIdx.x;
    float a = 0.f;
    #pragma unroll
    for (int s = 0; s < 32; s++) a += partC[(size_t)s * 18432 + id];
    P[id] = a;
  } else {
    int r = blk - 72;
    va2_body(r & 7, r >> 3, ytmp, rowptr, cols, vals, selfw, va2v, 1);
  }
}

// ---------------- k_y1: fused x2-on-the-fly + A-hop (VALU-bound 80us, proven optimal vs split) ----------------
__global__ __launch_bounds__(256) void k_y1(
    const float* __restrict__ va2v, const float* __restrict__ P,
    const float* __restrict__ wsum, const float* __restrict__ w2s,
    const float* __restrict__ b2,
    const int* __restrict__ rowptr, const int* __restrict__ cols,
    const float* __restrict__ vals, const float* __restrict__ selfw,
    unsigned short* __restrict__ Y){
  int dst = blockIdx.x;
  int batch = (blockIdx.y << 2) + (threadIdx.x >> 6);
  int f8 = (threadIdx.x & 63) * 8;
  float wv0[8], wv1[8], wv2[8], cc[8], bb[8], ii[8];
  #pragma unroll
  for (int j = 0; j < 8; j++){
    int fc = f8 + j;
    wv0[j] = P[512 + fc]; wv1[j] = P[1024 + fc]; wv2[j] = P[1536 + fc];
    cc[j]  = P[fc];       bb[j]  = b2[fc];
    ii[j]  = P[2048 + (size_t)batch * 512 + fc];
  }
  float acc[8] = {};
  int rs = rowptr[dst], re = rowptr[dst + 1];
  for (int e = rs - 1; e < re; e++){
    int s; float w;
    if (e < rs){ s = dst; w = selfw[dst]; }
    else       { s = cols[e]; w = vals[e]; }
    const float* va = va2v + ((size_t)s * 32 + batch) * 3;
    float x0 = va[0], x1 = va[1], x2 = va[2];
    float w2v = w2s[s], wsv = wsum[s];
    #pragma unroll
    for (int j = 0; j < 8; j++){
      float tv = x0*wv0[j] + x1*wv1[j] + x2*wv2[j] + w2v*ii[j] + wsv*cc[j] + bb[j];
      tv = fmaxf(tv, 0.f);
      acc[j] += w * tv;
    }
  }
  unsigned int o[4];
  #pragma unroll
  for (int i = 0; i < 4; i++)
    o[i] = (unsigned int)f2bf(acc[2*i]) | ((unsigned int)f2bf(acc[2*i+1]) << 16);
  *(uint4*)&Y[((size_t)dst * 32 + batch) * 512 + f8] = *(uint4*)o;
}

// ---------------- k_aggv: F=512 bf16 A-hop (proven 74us/hop = gather ceiling; CLOSED) ----------------
__global__ __launch_bounds__(128) void k_aggv(
    const unsigned short* __restrict__ Hg, const int* __restrict__ rowptr,
    const int* __restrict__ cols, const float* __restrict__ vals,
    const float* __restrict__ selfw, unsigned short* __restrict__ Xo){
  int bid = blockIdx.x;
  int bg  = bid & 7;
  int dst = (bid >> 3) & (V_ - 1);
  int fc  = bid >> 14;
  int t = threadIdx.x;
  int batch = (bg << 2) + (t >> 5);
  int f8 = (fc << 8) + (t & 31) * 8;
  int rs = rowptr[dst], re = rowptr[dst + 1];
  float sw = selfw[dst];
  float a[8];
  {
    uint4 q = *(const uint4*)&Hg[((size_t)dst * 32 + batch) * 512 + f8];
    const unsigned int* w = (const unsigned int*)&q;
    #pragma unroll
    for (int i = 0; i < 4; i++){
      a[2*i]   = sw * bf2f(w[i] & 0xffff);
      a[2*i+1] = sw * bf2f(w[i] >> 16);
    }
  }
  int e = rs;
  for (; e + 1 < re; e += 2){
    int s0 = cols[e], s1 = cols[e+1];
    float v0 = vals[e], v1 = vals[e+1];
    uint4 q0 = *(const uint4*)&Hg[((size_t)s0 * 32 + batch) * 512 + f8];
    uint4 q1 = *(const uint4*)&Hg[((size_t)s1 * 32 + batch) * 512 + f8];
    const unsigned int* w0 = (const unsigned int*)&q0;
    const unsigned int* w1 = (const unsigned int*)&q1;
    #pragma unroll
    for (int i = 0; i < 4; i++){
      a[2*i]   += v0 * bf2f(w0[i] & 0xffff) + v1 * bf2f(w1[i] & 0xffff);
      a[2*i+1] += v0 * bf2f(w0[i] >> 16)    + v1 * bf2f(w1[i] >> 16);
    }
  }
  if (e < re){
    int s = cols[e]; float v = vals[e];
    uint4 q = *(const uint4*)&Hg[((size_t)s * 32 + batch) * 512 + f8];
    const unsigned int* w = (const unsigned int*)&q;
    #pragma unroll
    for (int i = 0; i < 4; i++){
      a[2*i]   += v * bf2f(w[i] & 0xffff);
      a[2*i+1] += v * bf2f(w[i] >> 16);
    }
  }
  unsigned int o[4];
  #pragma unroll
  for (int i = 0; i < 4; i++)
    o[i] = (unsigned int)f2bf(a[2*i]) | ((unsigned int)f2bf(a[2*i+1]) << 16);
  *(uint4*)&Xo[((size_t)dst * 32 + batch) * 512 + f8] = *(uint4*)o;
}

// ---------------- k_xa2a / k_xa2b: layers 5+6 tail split into 2 kernels x 256 blocks ----------------
// xa2a sums TWO H5P partials (gemm now runs grid (512,2) with BN=256).
__global__ __launch_bounds__(256) void k_xa2a(
    const float* __restrict__ h5p, const int* __restrict__ rowptr,
    const int* __restrict__ cols, const float* __restrict__ vals,
    const float* __restrict__ selfw, float* __restrict__ yout){
  __shared__ float xs[V_ * 3];
  int b = blockIdx.y, t = threadIdx.x;
  const size_t M3 = (size_t)M_ * 3;
  for (int i = t; i < V_ * 3; i += 256){
    int v = i / 3, j = i - v * 3;
    size_t g = ((size_t)v * 32 + b) * 3 + j;
    xs[i] = h5p[g] + h5p[M3 + g];
  }
  __syncthreads();
  int v = blockIdx.x * 256 + t;
  float sw = selfw[v];
  float a0 = sw * xs[v*3], a1 = sw * xs[v*3+1], a2 = sw * xs[v*3+2];
  int re = rowptr[v + 1];
  for (int e = rowptr[v]; e < re; e++){
    int s = cols[e]; float vv = vals[e];
    a0 += vv * xs[s*3]; a1 += vv * xs[s*3+1]; a2 += vv * xs[s*3+2];
  }
  float* o = yout + (size_t)b * V_ * 3 + v * 3;
  o[0] = a0; o[1] = a1; o[2] = a2;
}

__global__ __launch_bounds__(256) void k_xa2b(
    const float* __restrict__ yin, const int* __restrict__ rowptr,
    const int* __restrict__ cols, const float* __restrict__ vals,
    const float* __restrict__ selfw, const float* __restrict__ wsum,
    const float* __restrict__ C56, const float* __restrict__ b6,
    float* __restrict__ XF){
  __shared__ float xs[V_ * 3];
  int b = blockIdx.y, t = threadIdx.x;
  const float* ib = yin + (size_t)b * V_ * 3;
  for (int i = t; i < V_ * 3; i += 256) xs[i] = ib[i];
  __syncthreads();
  int v = blockIdx.x * 256 + t;
  float sw = selfw[v];
  float a0 = sw * xs[v*3], a1 = sw * xs[v*3+1], a2 = sw * xs[v*3+2];
  int re = rowptr[v + 1];
  for (int e = rowptr[v]; e < re; e++){
    int s = cols[e]; float vv = vals[e];
    a0 += vv * xs[s*3]; a1 += vv * xs[s*3+1]; a2 += vv * xs[s*3+2];
  }
  float w = wsum[v];
  a0 = fmaxf(a0 + w * C56[0] + b6[0], 0.f);
  a1 = fmaxf(a1 + w * C56[1] + b6[1], 0.f);
  a2 = fmaxf(a2 + w * C56[2] + b6[2], 0.f);
  float* ob = XF + (size_t)b * V_ * 3 + v * 3;
  ob[0] = a0; ob[1] = a1; ob[2] = a2;
}

// ---------------- FC split-K stage A ----------------
template<int R, int KC>
__global__ __launch_bounds__(256) void k_fcp(
    const float* __restrict__ in, const float* __restrict__ W,
    float* __restrict__ partial, int K, int N){
  const int n = blockIdx.x * 256 + threadIdx.x;
  const int k0 = blockIdx.y * KC;
  float acc[R] = {};
  for (int kk = 0; kk < KC; kk += 4){
    const float* wp = W + (size_t)(k0 + kk) * N + n;
    float w0 = wp[0];
    float w1 = wp[(size_t)N];
    float w2 = wp[(size_t)2 * N];
    float w3 = wp[(size_t)3 * N];
    #pragma unroll
    for (int r = 0; r < R; r++){
      const float* xp = in + (size_t)r * K + k0 + kk;
      acc[r] += xp[0]*w0 + xp[1]*w1 + xp[2]*w2 + xp[3]*w3;
    }
  }
  float* p = partial + (size_t)blockIdx.y * R * N + n;
  #pragma unroll
  for (int r = 0; r < R; r++) p[(size_t)r * N] = acc[r];
}

// ---------------- FC split-K stage B ----------------
__global__ __launch_bounds__(256) void k_fcr(
    const float* __restrict__ partial, const float* __restrict__ bias,
    float* __restrict__ out, int total, int N, int KS, int mode,
    const float* __restrict__ vert){
  int id = blockIdx.x * 256 + threadIdx.x;
  if (id >= total) return;
  int n = id % N;
  float a0 = 0.f, a1 = 0.f, a2 = 0.f, a3 = 0.f;
  int s = 0;
  for (; s + 4 <= KS; s += 4){
    a0 += partial[(size_t)s * total + id];
    a1 += partial[(size_t)(s + 1) * total + id];
    a2 += partial[(size_t)(s + 2) * total + id];
    a3 += partial[(size_t)(s + 3) * total + id];
  }
  for (; s < KS; s++) a0 += partial[(size_t)s * total + id];
  float acc = a0 + a1 + a2 + a3;
  if (bias) acc += bias[n];
  if (mode) acc = vert[id] + 0.1f * tanhf(acc);
  out[id] = acc;
}

// ---------------- workspace layout ----------------
static constexpr size_t AL(size_t x){ return (x + 255) & ~(size_t)255; }
static constexpr size_t S512 = (size_t)M_ * 512 * 2;
static constexpr size_t S3   = (size_t)M_ * 3 * 4;
static constexpr size_t OXA  = 0;
static constexpr size_t OXB  = OXA  + AL(S512);
static constexpr size_t OVA2 = OXB  + AL(S512);
static constexpr size_t OH5P = OVA2 + AL(S3);
static constexpr size_t OXF  = OH5P + AL(4 * S3);
static constexpr size_t OFC1 = OXF  + AL(S3);
static constexpr size_t OFC2 = OFC1 + AL((size_t)B_ * 1024 * 4);
static constexpr size_t OI1  = OFC2 + AL((size_t)B_ * 1024 * 4);
static constexpr size_t OP   = OI1  + AL((size_t)32 * 512 * 4);
static constexpr size_t OC34 = OP   + AL((size_t)36 * 512 * 4);
static constexpr size_t OW56 = OC34 + AL((size_t)512 * 4);
static constexpr size_t OC56 = OW56 + AL((size_t)512 * 3 * 4);
static constexpr size_t OW3B = OC56 + AL((size_t)3 * 4);
static constexpr size_t OW4T = OW3B + AL((size_t)512 * 512 * 2);
static constexpr size_t OW34 = OW4T + AL((size_t)512 * 512 * 2);
static constexpr size_t OROW = OW34 + AL((size_t)512 * 512 * 2);
static constexpr size_t OCOL = OROW + AL((size_t)(V_ + 1) * 4);
static constexpr size_t OVAL = OCOL + AL((size_t)E_ * 4);
static constexpr size_t OSELF= OVAL + AL((size_t)E_ * 4);
static constexpr size_t OWS  = OSELF+ AL((size_t)V_ * 4);
static constexpr size_t OW2S = OWS  + AL((size_t)V_ * 4);

extern "C" void kernel_launch(void* const* d_in, const int* in_sizes, int n_in,
                              void* d_out, int out_size, void* d_ws, size_t ws_size,
                              hipStream_t stream){
  const float* vert  = (const float*)d_in[0];
  const float* img   = (const float*)d_in[1];
  const int*   ei    = (const int*)  d_in[2];
  const float* W1 = (const float*)d_in[3],  *b1 = (const float*)d_in[4];
  const float* W2 = (const float*)d_in[5],  *b2 = (const float*)d_in[6];
  const float* W3 = (const float*)d_in[7],  *b3 = (const float*)d_in[8];
  const float* W4 = (const float*)d_in[9],  *b4 = (const float*)d_in[10];
  const float* W5 = (const float*)d_in[11], *b5 = (const float*)d_in[12];
  const float* W6 = (const float*)d_in[13], *b6 = (const float*)d_in[14];
  const float* fcW1 = (const float*)d_in[15], *fcb1 = (const float*)d_in[16];
  const float* fcW2 = (const float*)d_in[17], *fcb2 = (const float*)d_in[18];
  const float* fcW3 = (const float*)d_in[19], *fcb3 = (const float*)d_in[20];
  float* out = (float*)d_out;

  char* ws = (char*)d_ws;
  unsigned short* XA  = (unsigned short*)(ws + OXA);
  unsigned short* XB  = (unsigned short*)(ws + OXB);
  float* VA2v = (float*)(ws + OVA2);
  float* H5P  = (float*)(ws + OH5P);
  float* XF   = (float*)(ws + OXF);
  float* FC1o = (float*)(ws + OFC1);
  float* FC2o = (float*)(ws + OFC2);
  float* P    = (float*)(ws + OP);
  float* C34  = (float*)(ws + OC34);
  float* W56  = (float*)(ws + OW56);
  float* C56  = (float*)(ws + OC56);
  unsigned short* W3B = (unsigned short*)(ws + OW3B);
  unsigned short* W4T = (unsigned short*)(ws + OW4T);
  unsigned short* W34 = (unsigned short*)(ws + OW34);
  float* PARTA = (float*)(ws + OXA);
  float* PARTB = (float*)(ws + OXB);
  float* PARTC = (float*)(ws + OXB) + (1 << 20);   // preC output, disjoint from I1 partials
  float* YTMP  = (float*)(ws + OXA);   // hop intermediate; OXA region idle at those points
  int*   ROW  = (int*)(ws + OROW);
  int*   COL  = (int*)(ws + OCOL);
  float* VAL  = (float*)(ws + OVAL);
  float* SELF = (float*)(ws + OSELF);
  float* WSUM = (float*)(ws + OWS);
  float* W2S  = (float*)(ws + OW2S);

  // ---- CSR (block 0) + preA (blocks 1..339, incl. folded C34/W56/C56) ----
  k_pre0<<<340, 1024, 0, stream>>>(ei, ROW, COL, VAL, SELF, WSUM, W2S,
                                   W3, W4, img, W1, b3, W5, W6, b5,
                                   W3B, W4T, PARTB, C34, W56, C56);

  // ---- mix1: W34 gemm (64) + preC (64) + va2a (256) -- mutually independent ----
  k_mix1<<<384, 256, 0, stream>>>(W4T, W3B, W34, b1, W1, W2, PARTB, PARTC,
                                  vert, ROW, COL, VAL, SELF, YTMP);
  // ---- mix2: preD (72) + va2b (256) ----
  k_mix2<<<328, 256, 0, stream>>>(PARTC, P, YTMP, ROW, COL, VAL, SELF, VA2v);

  // ---- layer 2 transform fused with first A-hop (k_y1), then second hop ----
  k_y1<<<dim3(V_, 8), 256, 0, stream>>>(VA2v, P, WSUM, W2S, b2, ROW, COL, VAL, SELF, XB);
  k_aggv<<<V_ * 16, 128, 0, stream>>>(XB, ROW, COL, VAL, SELF, XA);

  // ---- GEMM BN=256, 8 waves, grid (512,2): halves the XA re-read (256->128MB) ----
  k_gemm<128,256,2,4,4,4><<<dim3(M_ / 128, 2), 512, 0, stream>>>(XA, W34, XB, 512, 512,
                                                                 WSUM, C34, b4, 1,
                                                                 W56, H5P);

  // ---- layers 5+6 tail: split A^2 (F=3) + epilogue, 2 x 256 blocks ----
  k_xa2a<<<dim3(8, B_), 256, 0, stream>>>(H5P, ROW, COL, VAL, SELF, YTMP);
  k_xa2b<<<dim3(8, B_), 256, 0, stream>>>(YTMP, ROW, COL, VAL, SELF, WSUM, C56, b6, XF);

  // ---- FC head ----
  k_fcp<32,64><<<dim3(4, 96), 256, 0, stream>>>(XF, fcW1, PARTA, 6144, 1024);
  k_fcr<<<(B_ * 1024 + 255) / 256, 256, 0, stream>>>(PARTA, fcb1, FC1o, 32 * 1024, 1024, 96, 0, nullptr);
  k_fcp<32,64><<<dim3(4, 16), 256, 0, stream>>>(FC1o, fcW2, PARTA, 1024, 1024);
  k_fcr<<<(B_ * 1024 + 255) / 256, 256, 0, stream>>>(PARTA, fcb2, FC2o, 32 * 1024, 1024, 16, 0, nullptr);
  k_fcp<32,64><<<dim3(24, 16), 256, 0, stream>>>(FC2o, fcW3, PARTA, 1024, 6144);
  k_fcr<<<(B_ * 6144 + 255) / 256, 256, 0, stream>>>(PARTA, fcb3, out, 32 * 6144, 6144, 16, 1, vert);
}